// Round 4
// baseline (3557.365 us; speedup 1.0000x reference)
//
#include <hip/hip_runtime.h>
#include <math.h>

// Problem constants (fixed by reference)
#define BB      8
#define DD      384
#define FDIM    256
#define NPIX    4096
#define NHEAD   8
#define NCLOUD  4
#define HDIM    48
#define GSZ     1024
#define TT      (BB*NPIX)     // 32768 tokens
#define DHID    (4*DD)        // 1536

// ---------------- block reduction helper ----------------
__device__ __forceinline__ float block_sum(float v, float* sm, int nthreads){
    #pragma unroll
    for (int o = 32; o > 0; o >>= 1) v += __shfl_down(v, o, 64);
    int nw = nthreads >> 6;
    __syncthreads();
    if ((threadIdx.x & 63) == 0) sm[threadIdx.x >> 6] = v;
    __syncthreads();
    float s = sm[0];
    for (int i = 1; i < nw; i++) s += sm[i];
    return s;
}

// ---------------- tiny kernels ----------------
// film @ adaW.T + adab  for both ada1 and ada2   -> gb1[8][768], gb2[8][768]
__global__ void film_gemm(const float* film, const float* W1, const float* b1,
                          const float* W2, const float* b2, float* gb1, float* gb2){
    int idx = blockIdx.x * blockDim.x + threadIdx.x;        // 0..12287
    if (idx >= 2*BB*768) return;
    int which = idx / (BB*768);
    int r = idx % (BB*768);
    int bb = r / 768, j = r % 768;
    const float* W = which ? W2 : W1;
    const float* bi = which ? b2 : b1;
    const float* f = film + bb*FDIM;
    const float* w = W + (size_t)j*FDIM;
    float s = 0.f;
    for (int i = 0; i < FDIM; i++) s += f[i]*w[i];
    (which ? gb2 : gb1)[bb*768 + j] = s + bi[j];
}

__global__ void make_invp(const int* perm, int* invp){
    int i = blockIdx.x * blockDim.x + threadIdx.x;
    if (i < NPIX) invp[perm[i]] = i;
}

// gx[row] = sqrt(sum_pix x[row,pix]^2)  for row in [0, nb*DD)  (x pre-offset per pass)
__global__ void rownorm(const float* x, float* gx){
    __shared__ float sm[4];
    int row = blockIdx.x;
    const float* p = x + (size_t)row*NPIX;
    float s = 0.f;
    for (int i = threadIdx.x; i < NPIX; i += 256){ float v = p[i]; s += v*v; }
    float tot = block_sum(s, sm, 256);
    if (threadIdx.x == 0) gx[row] = sqrtf(tot);
}

// nx[b,d] = gx / (mean_d gx + 1e-6)   (grid = nb blocks of DD threads)
__global__ void grn_nx(const float* gx, float* nx){
    __shared__ float sm[6];
    int b = blockIdx.x; int d = threadIdx.x;   // 384 threads
    float g = gx[b*DD + d];
    float tot = block_sum(g, sm, 384);
    nx[b*DD + d] = g / (tot/(float)DD + 1e-6f);
}

// fused transpose + GRN1 + adaLN1:  xt[(b<<12)+pix, d] from img[b,d,pix]  (b pass-local)
__global__ void adaln1_transpose(const float* img, const float* nx,
                                 const float* gg, const float* gbv,
                                 const float* gb, float* xt){
    __shared__ float tile[32][33];
    int b = blockIdx.z, p0 = blockIdx.x*32, d0 = blockIdx.y*32;
    int tx = threadIdx.x, ty = threadIdx.y;     // 32 x 8
    #pragma unroll
    for (int i = 0; i < 32; i += 8)
        tile[ty+i][tx] = img[((size_t)b*DD + d0+ty+i)*NPIX + p0+tx];
    __syncthreads();
    #pragma unroll
    for (int i = 0; i < 32; i += 8){
        int p = p0 + ty + i;
        int d = d0 + tx;
        float v = tile[tx][ty+i];
        float g = v * nx[b*DD + d];
        float grn = (1.f + gg[d])*g + gbv[d] + v;
        xt[((size_t)(b<<12) + p)*DD + d] = grn*(1.f + gb[b*768 + d]) + gb[b*768 + 384 + d];
    }
}

// elementwise GRN2 + adaLN2 on token-major input (b pass-local)
__global__ void adaln_tok(const float* xin, const float* nx,
                          const float* gg, const float* gbv,
                          const float* gb, float* xout){
    size_t i = (size_t)blockIdx.x * blockDim.x + threadIdx.x;
    int d = (int)(i % DD); size_t t = i / DD; int b = (int)(t >> 12);
    float v = xin[i];
    float g = v * nx[b*DD + d];
    float grn = (1.f + gg[d])*g + gbv[d] + v;
    xout[i] = grn*(1.f + gb[b*768 + d]) + gb[b*768 + 384 + d];
}

// ---------------- generic fp32 GEMM:  C[M,N] = A[M,K] @ W[N,K]^T + bias ----------------
// optional A-row gather (pass-local): arow = (row & ~4095) | perm[row & 4095]
template<int EPI>   // 0 = none, 1 = silu
__global__ __launch_bounds__(256) void gemm_f32(const float* __restrict__ A,
                          const float* __restrict__ W,
                          const float* __restrict__ bias,
                          float* __restrict__ C,
                          int M, int N, int K, const int* __restrict__ rowmap){
    __shared__ float As[16][65];
    __shared__ float Ws[16][65];
    int tx = threadIdx.x & 15, ty = threadIdx.x >> 4;
    int m0 = blockIdx.y*64, n0 = blockIdx.x*64;
    float acc[4][4] = {};
    for (int k0 = 0; k0 < K; k0 += 16){
        #pragma unroll
        for (int i = 0; i < 4; i++){
            int r = ty + i*16;
            int row = m0 + r;
            int arow = row;
            if (rowmap){ int p = row & 4095; arow = (row & ~4095) + rowmap[p]; }
            As[tx][r] = A[(size_t)arow*K + k0 + tx];
            Ws[tx][r] = W[(size_t)(n0+r)*K + k0 + tx];
        }
        __syncthreads();
        #pragma unroll
        for (int kk = 0; kk < 16; kk++){
            float a[4], w[4];
            #pragma unroll
            for (int i = 0; i < 4; i++) a[i] = As[kk][ty + 16*i];
            #pragma unroll
            for (int j = 0; j < 4; j++) w[j] = Ws[kk][tx + 16*j];
            #pragma unroll
            for (int i = 0; i < 4; i++)
                #pragma unroll
                for (int j = 0; j < 4; j++)
                    acc[i][j] += a[i]*w[j];
        }
        __syncthreads();
    }
    #pragma unroll
    for (int i = 0; i < 4; i++){
        int m = m0 + ty + 16*i;
        #pragma unroll
        for (int j = 0; j < 4; j++){
            int n = n0 + tx + 16*j;
            float v = acc[i][j] + bias[n];
            if (EPI == 1) v = v / (1.f + expf(-v));
            C[(size_t)m*N + n] = v;
        }
    }
}

// LayerNorm over D=384 + elu + 1, in place.  128 threads/row.
__global__ void ln_elu(float* x, const float* g, const float* b){
    __shared__ float sm[2];
    int t = blockIdx.x;
    float* row = x + (size_t)t*DD;
    float v[3]; float s = 0.f;
    #pragma unroll
    for (int i = 0; i < 3; i++){ v[i] = row[threadIdx.x + 128*i]; s += v[i]; }
    float mean = block_sum(s, sm, 128) / (float)DD;
    float s2 = 0.f;
    #pragma unroll
    for (int i = 0; i < 3; i++){ float d = v[i]-mean; s2 += d*d; }
    float var = block_sum(s2, sm, 128) / (float)DD;
    float rstd = rsqrtf(var + 1e-5f);
    #pragma unroll
    for (int i = 0; i < 3; i++){
        int d = threadIdx.x + 128*i;
        float y = (v[i]-mean)*rstd*g[d] + b[d];
        y = (y > 0.f) ? y : expm1f(y);
        row[d] = y + 1.f;
    }
}

// kv[bc,h,e,f] = sum_n k[bc,n,h,e] v[bc,n,h,f];  ksum[bc,h,e] = sum_n k   (bc pass-local)
__global__ void kv_ksum(const float* k_, const float* v_, float* kv, float* ksum){
    int bc = blockIdx.x / NHEAD, h = blockIdx.x % NHEAD;
    __shared__ float ks[16][48];
    __shared__ float vs[16][48];
    int eq[9], fq[9];
    #pragma unroll
    for (int q = 0; q < 9; q++){ int pi = threadIdx.x*9 + q; eq[q] = pi/48; fq[q] = pi%48; }
    float acc[9] = {};
    float ksacc = 0.f;
    for (int n0 = 0; n0 < GSZ; n0 += 16){
        for (int i = threadIdx.x; i < 16*48; i += 256){
            int n = i/48, e = i%48;
            size_t base = ((size_t)(bc*GSZ + n0 + n))*DD + h*HDIM;
            ks[n][e] = k_[base + e];
            vs[n][e] = v_[base + e];
        }
        __syncthreads();
        #pragma unroll 4
        for (int n = 0; n < 16; n++){
            #pragma unroll
            for (int q = 0; q < 9; q++) acc[q] += ks[n][eq[q]] * vs[n][fq[q]];
        }
        if (threadIdx.x < 48){
            #pragma unroll 4
            for (int n = 0; n < 16; n++) ksacc += ks[n][threadIdx.x];
        }
        __syncthreads();
    }
    float* kvh = kv + ((size_t)(bc*NHEAD + h))*HDIM*HDIM;
    #pragma unroll
    for (int q = 0; q < 9; q++) kvh[eq[q]*HDIM + fq[q]] = acc[q];
    if (threadIdx.x < 48) ksum[(size_t)(bc*NHEAD + h)*HDIM + threadIdx.x] = ksacc;
}

// out[t, h*48+f] = (sum_e q[t,h,e] kv[bc,h,e,f]) / (sum_e q[t,h,e] ksum[bc,h,e] + 1e-8)
__global__ void attn_apply(const float* q_, const float* kv, const float* ksum, float* out){
    __shared__ float qs[DD];
    __shared__ float den_s[NHEAD];
    int t = blockIdx.x; int bc = t / GSZ;
    int tid = threadIdx.x;                  // 384
    qs[tid] = q_[(size_t)t*DD + tid];
    __syncthreads();
    int h = tid / HDIM, f = tid % HDIM;
    if (f == 0){
        const float* kse = ksum + (size_t)(bc*NHEAD + h)*HDIM;
        float s = 0.f;
        #pragma unroll
        for (int e = 0; e < HDIM; e++) s += qs[h*HDIM + e]*kse[e];
        den_s[h] = s + 1e-8f;
    }
    __syncthreads();
    const float* kvh = kv + ((size_t)(bc*NHEAD + h))*HDIM*HDIM + f;
    float num = 0.f;
    #pragma unroll
    for (int e = 0; e < HDIM; e++) num += qs[h*HDIM + e]*kvh[e*HDIM];
    out[(size_t)t*DD + tid] = num / den_s[h];
}

// wi[(b<<12)+pix, d] = img[b,d,pix] + aot[(b<<12)+invp[pix], d]*cs[d]   (b pass-local)
__global__ void build_wi(const float* img, const float* aot, const int* invp,
                         const float* cs, float* wi){
    __shared__ float tile[32][33];
    int b = blockIdx.z, p0 = blockIdx.x*32, d0 = blockIdx.y*32;
    int tx = threadIdx.x, ty = threadIdx.y;
    #pragma unroll
    for (int i = 0; i < 32; i += 8)
        tile[ty+i][tx] = img[((size_t)b*DD + d0+ty+i)*NPIX + p0+tx];
    __syncthreads();
    #pragma unroll
    for (int i = 0; i < 32; i += 8){
        int p = p0 + ty + i;
        int ttok = (b<<12) + invp[p];
        float a = aot[(size_t)ttok*DD + d0+tx];
        wi[((size_t)(b<<12) + p)*DD + d0+tx] = tile[tx][ty+i] + a*cs[d0+tx];
    }
}

// partial column sums of squares of token-major [nb*4096, D]
__global__ void colsq_partial(const float* x, float* partial){
    int b = blockIdx.x / 32, chunk = blockIdx.x % 32;
    float acc0 = 0.f, acc1 = 0.f;
    for (int r = 0; r < 128; r++){
        const float* row = x + ((size_t)((b<<12) + chunk*128 + r))*DD;
        float v = row[threadIdx.x]; acc0 += v*v;
        if (threadIdx.x < 128){ float w = row[threadIdx.x + 256]; acc1 += w*w; }
    }
    partial[(size_t)blockIdx.x*DD + threadIdx.x] = acc0;
    if (threadIdx.x < 128) partial[(size_t)blockIdx.x*DD + threadIdx.x + 256] = acc1;
}

__global__ void gx_from_partial(const float* partial, float* gx, int nd){
    int i = blockIdx.x * blockDim.x + threadIdx.x;
    if (i >= nd) return;
    int b = i / DD, d = i % DD;
    float s = 0.f;
    for (int c = 0; c < 32; c++) s += partial[((size_t)(b*32 + c))*DD + d];
    gx[i] = sqrtf(s);
}

// out[b,d,pix] = img + (wi + fot*ffs)[tok,d] * fins[d]   (b pass-local; img/out pre-offset)
__global__ void final_out(const float* img, const float* wi, const float* fot,
                          const float* ffs, const float* fins, float* out){
    __shared__ float tile[32][33];
    int b = blockIdx.z, p0 = blockIdx.x*32, d0 = blockIdx.y*32;
    int tx = threadIdx.x, ty = threadIdx.y;
    #pragma unroll
    for (int i = 0; i < 32; i += 8){
        size_t t = (size_t)(b<<12) + p0+ty+i;
        tile[ty+i][tx] = wi[t*DD + d0+tx] + fot[t*DD + d0+tx]*ffs[d0+tx];
    }
    __syncthreads();
    #pragma unroll
    for (int i = 0; i < 32; i += 8){
        int d = d0 + ty + i;
        size_t o = ((size_t)b*DD + d)*NPIX + p0+tx;
        out[o] = img[o] + tile[tx][ty+i]*fins[d];
    }
}

// ---------------- launch ----------------
extern "C" void kernel_launch(void* const* d_in, const int* in_sizes, int n_in,
                              void* d_out, int out_size, void* d_ws, size_t ws_size,
                              hipStream_t stream){
    const float* image   = (const float*)d_in[0];
    const float* film    = (const float*)d_in[1];
    const int*   perm    = (const int*)  d_in[2];
    const float* Wq      = (const float*)d_in[3];
    const float* bq      = (const float*)d_in[4];
    const float* Wk      = (const float*)d_in[5];
    const float* bk      = (const float*)d_in[6];
    const float* Wv      = (const float*)d_in[7];
    const float* bv      = (const float*)d_in[8];
    const float* Wo      = (const float*)d_in[9];
    const float* bo      = (const float*)d_in[10];
    const float* lnq_g   = (const float*)d_in[11];
    const float* lnq_b   = (const float*)d_in[12];
    const float* lnk_g   = (const float*)d_in[13];
    const float* lnk_b   = (const float*)d_in[14];
    const float* ada1_W  = (const float*)d_in[15];
    const float* ada1_b  = (const float*)d_in[16];
    const float* grn1_g  = (const float*)d_in[17];
    const float* grn1_b  = (const float*)d_in[18];
    const float* ada2_W  = (const float*)d_in[19];
    const float* ada2_b  = (const float*)d_in[20];
    const float* grn2_g  = (const float*)d_in[21];
    const float* grn2_b  = (const float*)d_in[22];
    const float* conv1_W = (const float*)d_in[23];
    const float* conv1_b = (const float*)d_in[24];
    const float* conv2_W = (const float*)d_in[25];
    const float* conv2_b = (const float*)d_in[26];
    const float* cs      = (const float*)d_in[27];
    const float* ffs     = (const float*)d_in[28];
    const float* fins    = (const float*)d_in[29];
    float* out = (float*)d_out;

    // ---- misc scratch (fixed layout, sized for the 8-batch worst case) ----
    char* m = (char*)d_ws;
    float* gb1     = (float*)m;  m += (size_t)BB*768*4;                    // 24576
    float* gb2     = (float*)m;  m += (size_t)BB*768*4;                    // 24576
    int*   invp    = (int*)m;    m += (size_t)NPIX*4;                      // 16384
    float* gx      = (float*)m;  m += (size_t)BB*DD*4;                     // 12288
    float* nx      = (float*)m;  m += (size_t)BB*DD*4;                     // 12288
    float* kvbuf   = (float*)m;  m += (size_t)BB*NCLOUD*NHEAD*HDIM*HDIM*4; // 2359296
    float* ksumbuf = (float*)m;  m += (size_t)BB*NCLOUD*NHEAD*HDIM*4;      // 49152
    float* partial = (float*)m;  m += (size_t)BB*32*DD*4;                  // 393216
    size_t misc_bytes = (size_t)(m - (char*)d_ws);                          // ~2.9 MB

    // choose batches-per-pass: largest nbp with misc + 6 fp32 token-major buffers fitting
    size_t unit1 = (size_t)NPIX*DD*sizeof(float);     // 6.29 MB per batch per buffer
    int nbp = 1;
    for (int c = 8; c >= 1; c >>= 1){
        if (ws_size >= misc_bytes + 6*(size_t)c*unit1){ nbp = c; break; }
    }
    size_t SZP = (size_t)nbp*unit1;

    float* A  = (float*)(m + 0*SZP);   // xt -> attn_out -> x2 -> fo
    float* Q  = (float*)(m + 1*SZP);   // q -> aot ; h1 spans Q..E (4*SZP)
    float* K  = (float*)(m + 2*SZP);   // k
    float* V  = (float*)(m + 3*SZP);   // v
    // E = 4*SZP..5*SZP: tail of h1 only
    float* WI = (float*)(m + 5*SZP);   // wi
    float* H1 = Q;                     // nbp*4096 x 1536 fp32 = 4*SZP exactly

    // ---- once: film projections + inverse permutation ----
    film_gemm<<<48, 256, 0, stream>>>(film, ada1_W, ada1_b, ada2_W, ada2_b, gb1, gb2);
    make_invp<<<16, 256, 0, stream>>>(perm, invp);

    for (int b0 = 0; b0 < BB; b0 += nbp){
        const float* img_b = image + (size_t)b0*DD*NPIX;
        float*       out_b = out   + (size_t)b0*DD*NPIX;
        const float* gb1_b = gb1 + b0*768;
        const float* gb2_b = gb2 + b0*768;
        int TP = nbp*NPIX;                            // tokens this pass

        // GRN1 stats + adaLN1 + transpose
        rownorm<<<nbp*DD, 256, 0, stream>>>(img_b, gx);
        grn_nx<<<nbp, DD, 0, stream>>>(gx, nx);
        adaln1_transpose<<<dim3(128,12,nbp), dim3(32,8), 0, stream>>>(img_b, nx, grn1_g, grn1_b, gb1_b, A);
        // QKV projections (A rows gathered through perm)
        gemm_f32<0><<<dim3(6,TP/64), 256, 0, stream>>>(A, Wq, bq, Q, TP, DD, DD, perm);
        gemm_f32<0><<<dim3(6,TP/64), 256, 0, stream>>>(A, Wk, bk, K, TP, DD, DD, perm);
        gemm_f32<0><<<dim3(6,TP/64), 256, 0, stream>>>(A, Wv, bv, V, TP, DD, DD, perm);
        // LN + elu + 1
        ln_elu<<<TP, 128, 0, stream>>>(Q, lnq_g, lnq_b);
        ln_elu<<<TP, 128, 0, stream>>>(K, lnk_g, lnk_b);
        // linear attention
        kv_ksum<<<nbp*NCLOUD*NHEAD, 256, 0, stream>>>(K, V, kvbuf, ksumbuf);
        attn_apply<<<TP, DD, 0, stream>>>(Q, kvbuf, ksumbuf, A);          // attn-out -> A
        // output projection -> aot in Q
        gemm_f32<0><<<dim3(6,TP/64), 256, 0, stream>>>(A, Wo, bo, Q, TP, DD, DD, nullptr);
        // un-permute + residual -> WI
        build_wi<<<dim3(128,12,nbp), dim3(32,8), 0, stream>>>(img_b, Q, invp, cs, WI);
        // GRN2 stats
        colsq_partial<<<nbp*32, 256, 0, stream>>>(WI, partial);
        gx_from_partial<<<(nbp*DD+255)/256, 256, 0, stream>>>(partial, gx, nbp*DD);
        grn_nx<<<nbp, DD, 0, stream>>>(gx, nx);
        // adaLN2 -> x2 in A
        adaln_tok<<<(size_t)TP*DD/256, 256, 0, stream>>>(WI, nx, grn2_g, grn2_b, gb2_b, A);
        // FFN: h1 overlays Q..E (q/k/v dead)
        gemm_f32<1><<<dim3(24,TP/64), 256, 0, stream>>>(A, conv1_W, conv1_b, H1, TP, DHID, DD, nullptr);
        gemm_f32<0><<<dim3(6,TP/64), 256, 0, stream>>>(H1, conv2_W, conv2_b, A, TP, DD, DHID, nullptr);
        // final residual + transpose back
        final_out<<<dim3(128,12,nbp), dim3(32,8), 0, stream>>>(img_b, WI, A, ffs, fins, out_b);
    }
}

// Round 5
// 916.940 us; speedup vs baseline: 3.8796x; 3.8796x over previous
//
#include <hip/hip_runtime.h>
#include <hip/hip_bf16.h>
#include <math.h>

// Problem constants (fixed by reference)
#define BB      8
#define DD      384
#define FDIM    256
#define NPIX    4096
#define NHEAD   8
#define NCLOUD  4
#define HDIM    48
#define GSZ     1024
#define TT      (BB*NPIX)     // 32768 tokens
#define DHID    (4*DD)        // 1536

typedef __hip_bfloat16 bf16;
typedef __attribute__((ext_vector_type(8))) short bf16x8;   // 8 bf16 = 4 VGPRs
typedef __attribute__((ext_vector_type(4))) float f32x4;

__device__ __forceinline__ float b2f(bf16 x){ return __bfloat162float(x); }
__device__ __forceinline__ bf16  f2b(float x){ return __float2bfloat16(x); }

// ---------------- block reduction helper ----------------
__device__ __forceinline__ float block_sum(float v, float* sm, int nthreads){
    #pragma unroll
    for (int o = 32; o > 0; o >>= 1) v += __shfl_down(v, o, 64);
    int nw = nthreads >> 6;
    __syncthreads();
    if ((threadIdx.x & 63) == 0) sm[threadIdx.x >> 6] = v;
    __syncthreads();
    float s = sm[0];
    for (int i = 1; i < nw; i++) s += sm[i];
    return s;
}

// ---------------- weight fp32 -> bf16 conversion (once per launch) ----------------
#define WSEG 147456            // 384*384
#define WBIG 589824            // 1536*384
__global__ void conv_w(const float* Wq, const float* Wk, const float* Wv, const float* Wo,
                       const float* W1, const float* W2, bf16* dst){
    int i = blockIdx.x*256 + threadIdx.x;          // < 1769472 exact
    float v;
    if      (i <   WSEG) v = Wq[i];
    else if (i < 2*WSEG) v = Wk[i -   WSEG];
    else if (i < 3*WSEG) v = Wv[i - 2*WSEG];
    else if (i < 4*WSEG) v = Wo[i - 3*WSEG];
    else if (i < 4*WSEG + WBIG) v = W1[i - 4*WSEG];
    else v = W2[i - 4*WSEG - WBIG];
    dst[i] = f2b(v);
}

// ---------------- tiny kernels ----------------
__global__ void film_gemm(const float* film, const float* W1, const float* b1,
                          const float* W2, const float* b2, float* gb1, float* gb2){
    int idx = blockIdx.x * blockDim.x + threadIdx.x;        // 0..12287
    if (idx >= 2*BB*768) return;
    int which = idx / (BB*768);
    int r = idx % (BB*768);
    int bb = r / 768, j = r % 768;
    const float* W = which ? W2 : W1;
    const float* bi = which ? b2 : b1;
    const float* f = film + bb*FDIM;
    const float* w = W + (size_t)j*FDIM;
    float s = 0.f;
    for (int i = 0; i < FDIM; i++) s += f[i]*w[i];
    (which ? gb2 : gb1)[bb*768 + j] = s + bi[j];
}

__global__ void make_invp(const int* perm, int* invp){
    int i = blockIdx.x * blockDim.x + threadIdx.x;
    if (i < NPIX) invp[perm[i]] = i;
}

// gx[b*D+d] = sqrt(sum_pix x[b,d,pix]^2)
__global__ void rownorm(const float* x, float* gx){
    __shared__ float sm[4];
    int row = blockIdx.x;
    const float* p = x + (size_t)row*NPIX;
    float s = 0.f;
    for (int i = threadIdx.x; i < NPIX; i += 256){ float v = p[i]; s += v*v; }
    float tot = block_sum(s, sm, 256);
    if (threadIdx.x == 0) gx[row] = sqrtf(tot);
}

__global__ void grn_nx(const float* gx, float* nx){
    __shared__ float sm[6];
    int b = blockIdx.x; int d = threadIdx.x;
    float g = gx[b*DD + d];
    float tot = block_sum(g, sm, 384);
    nx[b*DD + d] = g / (tot/(float)DD + 1e-6f);
}

// fused transpose + GRN1 + adaLN1 + pixel shuffle: writes bf16 rows in SHUFFLED token order
__global__ void adaln1_transpose(const float* img, const float* nx,
                                 const float* gg, const float* gbv,
                                 const float* gb, const int* invp, bf16* xt){
    __shared__ float tile[32][33];
    int b = blockIdx.z, p0 = blockIdx.x*32, d0 = blockIdx.y*32;
    int tx = threadIdx.x, ty = threadIdx.y;     // 32 x 8
    #pragma unroll
    for (int i = 0; i < 32; i += 8)
        tile[ty+i][tx] = img[((size_t)b*DD + d0+ty+i)*NPIX + p0+tx];
    __syncthreads();
    #pragma unroll
    for (int i = 0; i < 32; i += 8){
        int p = p0 + ty + i;
        int j = invp[p];                 // shuffled slot
        int d = d0 + tx;
        float v = tile[tx][ty+i];
        float g = v * nx[b*DD + d];
        float grn = (1.f + gg[d])*g + gbv[d] + v;
        xt[((size_t)(b<<12) + j)*DD + d] = f2b(grn*(1.f + gb[b*768 + d]) + gb[b*768 + 384 + d]);
    }
}

// elementwise GRN2 + adaLN2: fp32 in -> bf16 out
__global__ void adaln_tok(const float* xin, const float* nx,
                          const float* gg, const float* gbv,
                          const float* gb, bf16* xout){
    size_t i = (size_t)blockIdx.x * blockDim.x + threadIdx.x;
    int d = (int)(i % DD); size_t t = i / DD; int b = (int)(t >> 12);
    float v = xin[i];
    float g = v * nx[b*DD + d];
    float grn = (1.f + gg[d])*g + gbv[d] + v;
    xout[i] = f2b(grn*(1.f + gb[b*768 + d]) + gb[b*768 + 384 + d]);
}

// ---------------- MFMA bf16 GEMM:  C[M,N] = A[M,K] @ W[N,K]^T + bias ----------------
// 128x128 tile, BK=32, 4 waves (2x2), each wave 64x64 = 4x4 mfma 16x16x32 tiles.
template<int EPI>   // 0 = none, 1 = silu
__global__ __launch_bounds__(256) void gemm_mfma(const bf16* __restrict__ A,
                          const bf16* __restrict__ W,
                          const float* __restrict__ bias,
                          bf16* __restrict__ C,
                          int M, int N, int K){
    __shared__ short lds_[8192];                 // A: [0,4096) shorts, W: [4096,8192)
    int tid  = threadIdx.x;
    int lane = tid & 63, wid = tid >> 6;
    int quad = lane >> 4, l16 = lane & 15;
    int wm = (wid >> 1) * 64, wn = (wid & 1) * 64;
    int m0 = blockIdx.y * 128, n0 = blockIdx.x * 128;

    f32x4 acc[4][4] = {};
    for (int k0 = 0; k0 < K; k0 += 32){
        // stage A-tile + W-tile: 1024 slots x 16B
        #pragma unroll
        for (int it = 0; it < 4; it++){
            int s = tid + it*256;
            int half = s >> 9;
            int r = (s >> 2) & 127;
            int seg = s & 3;
            const bf16* src = half ? (W + (size_t)(n0 + r)*K + k0 + seg*8)
                                   : (A + (size_t)(m0 + r)*K + k0 + seg*8);
            *(bf16x8*)(void*)(lds_ + (size_t)s*8) = *(const bf16x8*)(const void*)src;
        }
        __syncthreads();
        bf16x8 af[4], wf[4];
        #pragma unroll
        for (int t = 0; t < 4; t++){
            af[t] = *(const bf16x8*)(void*)(lds_ + (wm + t*16 + l16)*32 + quad*8);
            wf[t] = *(const bf16x8*)(void*)(lds_ + 4096 + (wn + t*16 + l16)*32 + quad*8);
        }
        #pragma unroll
        for (int i = 0; i < 4; i++)
            #pragma unroll
            for (int j = 0; j < 4; j++)
                acc[i][j] = __builtin_amdgcn_mfma_f32_16x16x32_bf16(af[i], wf[j], acc[i][j], 0, 0, 0);
        __syncthreads();
    }
    // epilogue: row = m0+wm+i*16+quad*4+r, col = n0+wn+j*16+l16
    #pragma unroll
    for (int j = 0; j < 4; j++){
        int col = n0 + wn + j*16 + l16;
        float bs = bias[col];
        #pragma unroll
        for (int i = 0; i < 4; i++){
            int rowb = m0 + wm + i*16 + quad*4;
            #pragma unroll
            for (int r = 0; r < 4; r++){
                float v = acc[i][j][r] + bs;
                if (EPI == 1) v = v / (1.f + __expf(-v));
                C[(size_t)(rowb + r)*N + col] = f2b(v);
            }
        }
    }
}

// LayerNorm over D=384 + elu + 1, in place (bf16).  128 threads/row.
__global__ void ln_elu(bf16* x, const bf16* xin_unused, const float* g, const float* b){
    __shared__ float sm[2];
    int t = blockIdx.x;
    bf16* row = x + (size_t)t*DD;
    float v[3]; float s = 0.f;
    #pragma unroll
    for (int i = 0; i < 3; i++){ v[i] = b2f(row[threadIdx.x + 128*i]); s += v[i]; }
    float mean = block_sum(s, sm, 128) / (float)DD;
    float s2 = 0.f;
    #pragma unroll
    for (int i = 0; i < 3; i++){ float d = v[i]-mean; s2 += d*d; }
    float var = block_sum(s2, sm, 128) / (float)DD;
    float rstd = rsqrtf(var + 1e-5f);
    #pragma unroll
    for (int i = 0; i < 3; i++){
        int d = threadIdx.x + 128*i;
        float y = (v[i]-mean)*rstd*g[d] + b[d];
        y = (y > 0.f) ? y : expm1f(y);
        row[d] = f2b(y + 1.f);
    }
}

// kv[bc,h,e,f] = sum_n k[bc,n,h,e] v[bc,n,h,f];  ksum[bc,h,e] = sum_n k
__global__ void kv_ksum(const bf16* k_, const bf16* v_, float* kv, float* ksum){
    int bc = blockIdx.x / NHEAD, h = blockIdx.x % NHEAD;
    __shared__ float ks[16][48];
    __shared__ float vs[16][48];
    int eq[9], fq[9];
    #pragma unroll
    for (int q = 0; q < 9; q++){ int pi = threadIdx.x*9 + q; eq[q] = pi/48; fq[q] = pi%48; }
    float acc[9] = {};
    float ksacc = 0.f;
    for (int n0 = 0; n0 < GSZ; n0 += 16){
        for (int i = threadIdx.x; i < 16*48; i += 256){
            int n = i/48, e = i%48;
            size_t base = ((size_t)(bc*GSZ + n0 + n))*DD + h*HDIM;
            ks[n][e] = b2f(k_[base + e]);
            vs[n][e] = b2f(v_[base + e]);
        }
        __syncthreads();
        #pragma unroll 4
        for (int n = 0; n < 16; n++){
            #pragma unroll
            for (int q = 0; q < 9; q++) acc[q] += ks[n][eq[q]] * vs[n][fq[q]];
        }
        if (threadIdx.x < 48){
            #pragma unroll 4
            for (int n = 0; n < 16; n++) ksacc += ks[n][threadIdx.x];
        }
        __syncthreads();
    }
    float* kvh = kv + ((size_t)(bc*NHEAD + h))*HDIM*HDIM;
    #pragma unroll
    for (int q = 0; q < 9; q++) kvh[eq[q]*HDIM + fq[q]] = acc[q];
    if (threadIdx.x < 48) ksum[(size_t)(bc*NHEAD + h)*HDIM + threadIdx.x] = ksacc;
}

// attention apply: one block per (bc, h); kv tile resident in LDS.
__global__ __launch_bounds__(256) void attn_apply(const bf16* q_, const float* kv,
                                                  const float* ksum, bf16* out){
    __shared__ float kvs[HDIM*HDIM];
    __shared__ float kss[HDIM];
    __shared__ float qrow[16][HDIM+2];
    __shared__ float dens[16];
    int bc = blockIdx.x >> 3, h = blockIdx.x & 7;
    const float* kvh = kv + (size_t)(bc*NHEAD + h)*HDIM*HDIM;
    for (int i = threadIdx.x; i < HDIM*HDIM; i += 256) kvs[i] = kvh[i];
    if (threadIdx.x < HDIM) kss[threadIdx.x] = ksum[(size_t)(bc*NHEAD + h)*HDIM + threadIdx.x];
    __syncthreads();
    int rr = threadIdx.x >> 4;      // 0..15
    int ff = threadIdx.x & 15;      // 0..15
    for (int r0 = 0; r0 < GSZ; r0 += 16){
        for (int i = threadIdx.x; i < 16*HDIM; i += 256){
            int r = i/HDIM, e = i%HDIM;
            qrow[r][e] = b2f(q_[(size_t)(bc*GSZ + r0 + r)*DD + h*HDIM + e]);
        }
        __syncthreads();
        if (ff == 0){
            float s = 0.f;
            #pragma unroll
            for (int e = 0; e < HDIM; e++) s += qrow[rr][e]*kss[e];
            dens[rr] = s + 1e-8f;
        }
        __syncthreads();
        float inv = 1.f / dens[rr];
        float o0 = 0.f, o1 = 0.f, o2 = 0.f;
        #pragma unroll 8
        for (int e = 0; e < HDIM; e++){
            float qe = qrow[rr][e];
            o0 += qe*kvs[e*HDIM + ff];
            o1 += qe*kvs[e*HDIM + ff + 16];
            o2 += qe*kvs[e*HDIM + ff + 32];
        }
        bf16* orow = out + (size_t)(bc*GSZ + r0 + rr)*DD + h*HDIM;
        orow[ff]      = f2b(o0*inv);
        orow[ff + 16] = f2b(o1*inv);
        orow[ff + 32] = f2b(o2*inv);
        __syncthreads();
    }
}

// wi[(b<<12)+pix, d] = img[b,d,pix] + aot[(b<<12)+invp[pix], d]*cs[d]
__global__ void build_wi(const float* img, const bf16* aot, const int* invp,
                         const float* cs, float* wi){
    __shared__ float tile[32][33];
    int b = blockIdx.z, p0 = blockIdx.x*32, d0 = blockIdx.y*32;
    int tx = threadIdx.x, ty = threadIdx.y;
    #pragma unroll
    for (int i = 0; i < 32; i += 8)
        tile[ty+i][tx] = img[((size_t)b*DD + d0+ty+i)*NPIX + p0+tx];
    __syncthreads();
    #pragma unroll
    for (int i = 0; i < 32; i += 8){
        int p = p0 + ty + i;
        int ttok = (b<<12) + invp[p];
        float a = b2f(aot[(size_t)ttok*DD + d0+tx]);
        wi[((size_t)(b<<12) + p)*DD + d0+tx] = tile[tx][ty+i] + a*cs[d0+tx];
    }
}

// partial column sums of squares of token-major [T, D] fp32
__global__ void colsq_partial(const float* x, float* partial){
    int b = blockIdx.x / 32, chunk = blockIdx.x % 32;
    float acc0 = 0.f, acc1 = 0.f;
    for (int r = 0; r < 128; r++){
        const float* row = x + ((size_t)((b<<12) + chunk*128 + r))*DD;
        float v = row[threadIdx.x]; acc0 += v*v;
        if (threadIdx.x < 128){ float w = row[threadIdx.x + 256]; acc1 += w*w; }
    }
    partial[(size_t)blockIdx.x*DD + threadIdx.x] = acc0;
    if (threadIdx.x < 128) partial[(size_t)blockIdx.x*DD + threadIdx.x + 256] = acc1;
}

__global__ void gx_from_partial(const float* partial, float* gx, int nd){
    int i = blockIdx.x * blockDim.x + threadIdx.x;
    if (i >= nd) return;
    int b = i / DD, d = i % DD;
    float s = 0.f;
    for (int c = 0; c < 32; c++) s += partial[((size_t)(b*32 + c))*DD + d];
    gx[i] = sqrtf(s);
}

// out[b,d,pix] = img + (wi + fot*ffs)[tok,d] * fins[d]
__global__ void final_out(const float* img, const float* wi, const bf16* fot,
                          const float* ffs, const float* fins, float* out){
    __shared__ float tile[32][33];
    int b = blockIdx.z, p0 = blockIdx.x*32, d0 = blockIdx.y*32;
    int tx = threadIdx.x, ty = threadIdx.y;
    #pragma unroll
    for (int i = 0; i < 32; i += 8){
        size_t t = (size_t)(b<<12) + p0+ty+i;
        tile[ty+i][tx] = wi[t*DD + d0+tx] + b2f(fot[t*DD + d0+tx])*ffs[d0+tx];
    }
    __syncthreads();
    #pragma unroll
    for (int i = 0; i < 32; i += 8){
        int d = d0 + ty + i;
        size_t o = ((size_t)b*DD + d)*NPIX + p0+tx;
        out[o] = img[o] + tile[tx][ty+i]*fins[d];
    }
}

// ---------------- launch ----------------
extern "C" void kernel_launch(void* const* d_in, const int* in_sizes, int n_in,
                              void* d_out, int out_size, void* d_ws, size_t ws_size,
                              hipStream_t stream){
    const float* image   = (const float*)d_in[0];
    const float* film    = (const float*)d_in[1];
    const int*   perm    = (const int*)  d_in[2];
    const float* Wq      = (const float*)d_in[3];
    const float* bq      = (const float*)d_in[4];
    const float* Wk      = (const float*)d_in[5];
    const float* bk      = (const float*)d_in[6];
    const float* Wv      = (const float*)d_in[7];
    const float* bv      = (const float*)d_in[8];
    const float* Wo      = (const float*)d_in[9];
    const float* bo      = (const float*)d_in[10];
    const float* lnq_g   = (const float*)d_in[11];
    const float* lnq_b   = (const float*)d_in[12];
    const float* lnk_g   = (const float*)d_in[13];
    const float* lnk_b   = (const float*)d_in[14];
    const float* ada1_W  = (const float*)d_in[15];
    const float* ada1_b  = (const float*)d_in[16];
    const float* grn1_g  = (const float*)d_in[17];
    const float* grn1_b  = (const float*)d_in[18];
    const float* ada2_W  = (const float*)d_in[19];
    const float* ada2_b  = (const float*)d_in[20];
    const float* grn2_g  = (const float*)d_in[21];
    const float* grn2_b  = (const float*)d_in[22];
    const float* conv1_W = (const float*)d_in[23];
    const float* conv1_b = (const float*)d_in[24];
    const float* conv2_W = (const float*)d_in[25];
    const float* conv2_b = (const float*)d_in[26];
    const float* cs      = (const float*)d_in[27];
    const float* ffs     = (const float*)d_in[28];
    const float* fins    = (const float*)d_in[29];
    float* out = (float*)d_out;

    // ---- workspace layout (~183 MB; round-4 evidence: ws >= 305 MB) ----
    char* m = (char*)d_ws;
    float* gb1     = (float*)m;  m += (size_t)BB*768*4;
    float* gb2     = (float*)m;  m += (size_t)BB*768*4;
    int*   invp    = (int*)m;    m += (size_t)NPIX*4;
    float* gx      = (float*)m;  m += (size_t)BB*DD*4;
    float* nx      = (float*)m;  m += (size_t)BB*DD*4;
    float* kvbuf   = (float*)m;  m += (size_t)BB*NCLOUD*NHEAD*HDIM*HDIM*4;
    float* ksumbuf = (float*)m;  m += (size_t)BB*NCLOUD*NHEAD*HDIM*4;
    float* partial = (float*)m;  m += (size_t)BB*32*DD*4;
    bf16*  wb      = (bf16*)m;   m += (size_t)(4*WSEG + 2*WBIG)*2;   // all weights bf16
    bf16*  wbq = wb, *wbk = wb + WSEG, *wbv = wb + 2*WSEG, *wbo = wb + 3*WSEG;
    bf16*  wb1 = wb + 4*WSEG, *wb2 = wb + 4*WSEG + WBIG;
    float* wi      = (float*)m;  m += (size_t)TT*DD*4;               // 50.3 MB fp32
    const size_t SZB = (size_t)TT*DD*2;                              // 25.2 MB bf16
    bf16* Abf = (bf16*)(m + 0*SZB);    // xt(shuffled) -> attn_out -> x2 -> fo
    bf16* Qb  = (bf16*)(m + 1*SZB);    // q -> aot ; h1 spans Qb..Qb+4*SZB
    bf16* Kb  = (bf16*)(m + 2*SZB);
    bf16* Vb  = (bf16*)(m + 3*SZB);
    bf16* H1  = Qb;                    // 32768 x 1536 bf16 = 4*SZB exactly

    // ---- prologue ----
    conv_w<<<6912, 256, 0, stream>>>(Wq, Wk, Wv, Wo, conv1_W, conv2_W, wb);
    film_gemm<<<48, 256, 0, stream>>>(film, ada1_W, ada1_b, ada2_W, ada2_b, gb1, gb2);
    make_invp<<<16, 256, 0, stream>>>(perm, invp);

    // ---- branch 1: cloud attention ----
    rownorm<<<BB*DD, 256, 0, stream>>>(image, gx);
    grn_nx<<<BB, DD, 0, stream>>>(gx, nx);
    adaln1_transpose<<<dim3(128,12,BB), dim3(32,8), 0, stream>>>(image, nx, grn1_g, grn1_b, gb1, invp, Abf);
    gemm_mfma<0><<<dim3(3,256), 256, 0, stream>>>(Abf, wbq, bq, Qb, TT, DD, DD);
    gemm_mfma<0><<<dim3(3,256), 256, 0, stream>>>(Abf, wbk, bk, Kb, TT, DD, DD);
    gemm_mfma<0><<<dim3(3,256), 256, 0, stream>>>(Abf, wbv, bv, Vb, TT, DD, DD);
    ln_elu<<<TT, 128, 0, stream>>>(Qb, nullptr, lnq_g, lnq_b);
    ln_elu<<<TT, 128, 0, stream>>>(Kb, nullptr, lnk_g, lnk_b);
    kv_ksum<<<BB*NCLOUD*NHEAD, 256, 0, stream>>>(Kb, Vb, kvbuf, ksumbuf);
    attn_apply<<<BB*NCLOUD*NHEAD, 256, 0, stream>>>(Qb, kvbuf, ksumbuf, Abf);   // attn-out -> Abf
    gemm_mfma<0><<<dim3(3,256), 256, 0, stream>>>(Abf, wbo, bo, Qb, TT, DD, DD); // aot -> Qb
    build_wi<<<dim3(128,12,BB), dim3(32,8), 0, stream>>>(image, Qb, invp, cs, wi);

    // ---- branch 2: FFN ----
    colsq_partial<<<BB*32, 256, 0, stream>>>(wi, partial);
    gx_from_partial<<<12, 256, 0, stream>>>(partial, gx, BB*DD);
    grn_nx<<<BB, DD, 0, stream>>>(gx, nx);
    adaln_tok<<<(TT*DD)/256, 256, 0, stream>>>(wi, nx, grn2_g, grn2_b, gb2, Abf);  // x2 -> Abf
    gemm_mfma<1><<<dim3(12,256), 256, 0, stream>>>(Abf, wb1, conv1_b, H1, TT, DHID, DD);
    gemm_mfma<0><<<dim3(3,256), 256, 0, stream>>>(H1, wb2, conv2_b, Abf, TT, DD, DHID); // fo -> Abf
    final_out<<<dim3(128,12,BB), dim3(32,8), 0, stream>>>(image, wi, Abf, ffs, fins, out);
}

// Round 6
// 686.590 us; speedup vs baseline: 5.1812x; 1.3355x over previous
//
#include <hip/hip_runtime.h>
#include <hip/hip_bf16.h>
#include <math.h>

#define BB      8
#define DD      384
#define FDIM    256
#define NPIX    4096
#define NHEAD   8
#define NCLOUD  4
#define HDIM    48
#define GSZ     1024
#define TT      (BB*NPIX)     // 32768 tokens
#define DHID    (4*DD)        // 1536
#define TD      1152          // qkv fused row stride

typedef __hip_bfloat16 bf16;
typedef __attribute__((ext_vector_type(8))) short bf16x8;
typedef __attribute__((ext_vector_type(4))) float f32x4;

__device__ __forceinline__ float b2f(bf16 x){ return __bfloat162float(x); }
__device__ __forceinline__ bf16  f2b(float x){ return __float2bfloat16(x); }

#if defined(__has_builtin)
#if __has_builtin(__builtin_amdgcn_global_load_lds)
#define USE_GLL 1
#endif
#endif
#ifndef USE_GLL
#define USE_GLL 0
#endif

typedef __attribute__((address_space(1))) void gas_t;
typedef __attribute__((address_space(3))) void las_t;
__device__ __forceinline__ void gload16(const void* g, void* l){
#if USE_GLL
    __builtin_amdgcn_global_load_lds((gas_t*)(void*)g, (las_t*)l, 16, 0, 0);
#else
    *(bf16x8*)l = *(const bf16x8*)g;
#endif
}

// ---------------- block reduction helper ----------------
__device__ __forceinline__ float block_sum(float v, float* sm, int nthreads){
    #pragma unroll
    for (int o = 32; o > 0; o >>= 1) v += __shfl_down(v, o, 64);
    int nw = nthreads >> 6;
    __syncthreads();
    if ((threadIdx.x & 63) == 0) sm[threadIdx.x >> 6] = v;
    __syncthreads();
    float s = sm[0];
    for (int i = 1; i < nw; i++) s += sm[i];
    return s;
}

// ---------------- weight fp32 -> bf16 (once per launch) ----------------
#define WSEG 147456            // 384*384
#define WBIG 589824            // 1536*384
__global__ void conv_w(const float* Wq, const float* Wk, const float* Wv, const float* Wo,
                       const float* W1, const float* W2, bf16* dst){
    int i = blockIdx.x*256 + threadIdx.x;          // < 1769472 exact
    float v;
    if      (i <   WSEG) v = Wq[i];
    else if (i < 2*WSEG) v = Wk[i -   WSEG];
    else if (i < 3*WSEG) v = Wv[i - 2*WSEG];
    else if (i < 4*WSEG) v = Wo[i - 3*WSEG];
    else if (i < 4*WSEG + WBIG) v = W1[i - 4*WSEG];
    else v = W2[i - 4*WSEG - WBIG];
    dst[i] = f2b(v);
}

__global__ void make_bias(const float* bq, const float* bk, const float* bv, float* bqkv){
    int i = blockIdx.x*256 + threadIdx.x;
    if (i < 384) bqkv[i] = bq[i];
    else if (i < 768) bqkv[i] = bk[i-384];
    else if (i < 1152) bqkv[i] = bv[i-768];
}

// ---------------- tiny kernels ----------------
__global__ void film_gemm(const float* film, const float* W1, const float* b1,
                          const float* W2, const float* b2, float* gb1, float* gb2){
    int idx = blockIdx.x * blockDim.x + threadIdx.x;
    if (idx >= 2*BB*768) return;
    int which = idx / (BB*768);
    int r = idx % (BB*768);
    int bb = r / 768, j = r % 768;
    const float* W = which ? W2 : W1;
    const float* bi = which ? b2 : b1;
    const float* f = film + bb*FDIM;
    const float* w = W + (size_t)j*FDIM;
    float s = 0.f;
    for (int i = 0; i < FDIM; i++) s += f[i]*w[i];
    (which ? gb2 : gb1)[bb*768 + j] = s + bi[j];
}

__global__ void make_invp(const int* perm, int* invp){
    int i = blockIdx.x * blockDim.x + threadIdx.x;
    if (i < NPIX) invp[perm[i]] = i;
}

// gx[b*D+d] = sqrt(sum_pix x^2), float4 loads
__global__ void rownorm(const float* x, float* gx){
    __shared__ float sm[4];
    int row = blockIdx.x;
    const float4* p = (const float4*)(x + (size_t)row*NPIX);
    float s = 0.f;
    for (int i = threadIdx.x; i < NPIX/4; i += 256){
        float4 v = p[i];
        s += v.x*v.x + v.y*v.y + v.z*v.z + v.w*v.w;
    }
    float tot = block_sum(s, sm, 256);
    if (threadIdx.x == 0) gx[row] = sqrtf(tot);
}

__global__ void grn_nx(const float* gx, float* nx){
    __shared__ float sm[6];
    int b = blockIdx.x; int d = threadIdx.x;
    float g = gx[b*DD + d];
    float tot = block_sum(g, sm, 384);
    nx[b*DD + d] = g / (tot/(float)DD + 1e-6f);
}

// transpose + GRN1 + adaLN1 + pixel shuffle -> bf16 rows in SHUFFLED order
__global__ void adaln1_transpose(const float* img, const float* nx,
                                 const float* gg, const float* gbv,
                                 const float* gb, const int* invp, bf16* xt){
    __shared__ float tile[32][33];
    int b = blockIdx.z, p0 = blockIdx.x*32, d0 = blockIdx.y*32;
    int tx = threadIdx.x, ty = threadIdx.y;
    #pragma unroll
    for (int i = 0; i < 32; i += 8)
        tile[ty+i][tx] = img[((size_t)b*DD + d0+ty+i)*NPIX + p0+tx];
    __syncthreads();
    #pragma unroll
    for (int i = 0; i < 32; i += 8){
        int p = p0 + ty + i;
        int j = invp[p];
        int d = d0 + tx;
        float v = tile[tx][ty+i];
        float g = v * nx[b*DD + d];
        float grn = (1.f + gg[d])*g + gbv[d] + v;
        xt[((size_t)(b<<12) + j)*DD + d] = f2b(grn*(1.f + gb[b*768 + d]) + gb[b*768 + 384 + d]);
    }
}

// GRN2 + adaLN2: fp32 in -> bf16 out
__global__ void adaln_tok(const float* xin, const float* nx,
                          const float* gg, const float* gbv,
                          const float* gb, bf16* xout){
    size_t i = (size_t)blockIdx.x * blockDim.x + threadIdx.x;
    int d = (int)(i % DD); size_t t = i / DD; int b = (int)(t >> 12);
    float v = xin[i];
    float g = v * nx[b*DD + d];
    float grn = (1.f + gg[d])*g + gbv[d] + v;
    xout[i] = f2b(grn*(1.f + gb[b*768 + d]) + gb[b*768 + 384 + d]);
}

// ---------------- MFMA bf16 GEMM:  C = A[M,K] @ W[N,K]^T + bias ----------------
// 128x128 tile, BK=32, 4 waves 2x2, global_load_lds staging.
// optional rowmap: C row scatter  grow = (row & ~4095) | rowmap[row & 4095]
template<int EPI>   // 0 none, 1 silu
__global__ __launch_bounds__(256) void gemm_mfma(const bf16* __restrict__ A,
                          const bf16* __restrict__ W,
                          const float* __restrict__ bias,
                          bf16* __restrict__ C,
                          int M, int N, int K, const int* __restrict__ rowmap){
    __shared__ short lds_[8192];
    int tid  = threadIdx.x;
    int lane = tid & 63, wid = tid >> 6;
    int quad = lane >> 4, l16 = lane & 15;
    int wm = (wid >> 1) * 64, wn = (wid & 1) * 64;
    int m0 = blockIdx.y * 128, n0 = blockIdx.x * 128;

    f32x4 acc[4][4] = {};
    for (int k0 = 0; k0 < K; k0 += 32){
        #pragma unroll
        for (int it = 0; it < 4; it++){
            int s = tid + it*256;
            int half = s >> 9;
            int r = (s >> 2) & 127;
            int seg = s & 3;
            const bf16* src = half ? (W + (size_t)(n0 + r)*K + k0 + seg*8)
                                   : (A + (size_t)(m0 + r)*K + k0 + seg*8);
            gload16(src, lds_ + (size_t)s*8);
        }
        __syncthreads();
        bf16x8 af[4], wf[4];
        #pragma unroll
        for (int t = 0; t < 4; t++){
            af[t] = *(const bf16x8*)(void*)(lds_ + (wm + t*16 + l16)*32 + quad*8);
            wf[t] = *(const bf16x8*)(void*)(lds_ + 4096 + (wn + t*16 + l16)*32 + quad*8);
        }
        #pragma unroll
        for (int i = 0; i < 4; i++)
            #pragma unroll
            for (int j = 0; j < 4; j++)
                acc[i][j] = __builtin_amdgcn_mfma_f32_16x16x32_bf16(af[i], wf[j], acc[i][j], 0, 0, 0);
        __syncthreads();
    }
    #pragma unroll
    for (int j = 0; j < 4; j++){
        int col = n0 + wn + j*16 + l16;
        float bs = bias[col];
        #pragma unroll
        for (int i = 0; i < 4; i++){
            int rowb = m0 + wm + i*16 + quad*4;
            #pragma unroll
            for (int r = 0; r < 4; r++){
                int row = rowb + r;
                int grow = rowmap ? ((row & ~4095) | rowmap[row & 4095]) : row;
                float v = acc[i][j][r] + bs;
                if (EPI == 1) v = v / (1.f + __expf(-v));
                C[(size_t)grow*N + col] = f2b(v);
            }
        }
    }
}

// LN over D=384 + elu + 1 for q and k inside fused qkv buffer. One wave per row.
__global__ __launch_bounds__(256) void ln_elu_qk(bf16* qkv,
                        const float* gq, const float* bq2,
                        const float* gk, const float* bk2){
    int r = blockIdx.x*4 + (threadIdx.x >> 6);     // 0 .. 2*TT
    int lane = threadIdx.x & 63;
    int t = r >> 1, which = r & 1;
    bf16* row = qkv + (size_t)t*TD + which*384;
    const float* g = which ? gk : gq;
    const float* b = which ? bk2 : bq2;
    float v[6]; float s = 0.f;
    #pragma unroll
    for (int i = 0; i < 6; i++){ v[i] = b2f(row[lane + 64*i]); s += v[i]; }
    #pragma unroll
    for (int o = 32; o > 0; o >>= 1) s += __shfl_xor(s, o, 64);
    float mean = s / (float)DD;
    float s2 = 0.f;
    #pragma unroll
    for (int i = 0; i < 6; i++){ float d = v[i]-mean; s2 += d*d; }
    #pragma unroll
    for (int o = 32; o > 0; o >>= 1) s2 += __shfl_xor(s2, o, 64);
    float rstd = rsqrtf(s2/(float)DD + 1e-5f);
    #pragma unroll
    for (int i = 0; i < 6; i++){
        int d = lane + 64*i;
        float y = (v[i]-mean)*rstd*g[d] + b[d];
        y = (y > 0.f) ? y : expm1f(y);
        row[d] = f2b(y + 1.f);
    }
}

// kv partial: blockIdx = bch*8 + sub; each handles 128 n-rows; 3x3 register tile.
__global__ __launch_bounds__(256) void kv_ksum_part(const bf16* qkv, float* kvp, float* ksp){
    int bch = blockIdx.x >> 3, sub = blockIdx.x & 7;
    int bc = bch >> 3, h = bch & 7;
    __shared__ float ks[16][49];
    __shared__ float vs[16][49];
    int eg = (threadIdx.x >> 4) * 3;
    int fg = (threadIdx.x & 15) * 3;
    float acc[3][3] = {};
    float ksacc[3] = {};
    int nbase = bc*GSZ + sub*128;
    for (int n0 = 0; n0 < 128; n0 += 16){
        for (int i = threadIdx.x; i < 16*48; i += 256){
            int n = i/48, e = i%48;
            size_t base = (size_t)(nbase + n0 + n)*TD + h*HDIM;
            ks[n][e] = b2f(qkv[base + 384 + e]);
            vs[n][e] = b2f(qkv[base + 768 + e]);
        }
        __syncthreads();
        #pragma unroll 4
        for (int n = 0; n < 16; n++){
            float ka[3], vb[3];
            #pragma unroll
            for (int i = 0; i < 3; i++){ ka[i] = ks[n][eg+i]; vb[i] = vs[n][fg+i]; }
            #pragma unroll
            for (int i = 0; i < 3; i++)
                #pragma unroll
                for (int j = 0; j < 3; j++)
                    acc[i][j] += ka[i]*vb[j];
            if ((threadIdx.x & 15) == 0){
                #pragma unroll
                for (int i = 0; i < 3; i++) ksacc[i] += ka[i];
            }
        }
        __syncthreads();
    }
    float* kvo = kvp + (size_t)blockIdx.x*2304;
    #pragma unroll
    for (int i = 0; i < 3; i++)
        #pragma unroll
        for (int j = 0; j < 3; j++)
            kvo[(eg+i)*48 + fg+j] = acc[i][j];
    if ((threadIdx.x & 15) == 0){
        #pragma unroll
        for (int i = 0; i < 3; i++) ksp[(size_t)blockIdx.x*48 + eg+i] = ksacc[i];
    }
}

__global__ void kv_reduce(const float* kvp, const float* ksp, float* kv, float* ksum){
    int idx = blockIdx.x*256 + threadIdx.x;
    if (idx < 256*2304){
        int bch = idx / 2304, r = idx - bch*2304;
        const float* p = kvp + (size_t)bch*8*2304 + r;
        float s = 0.f;
        #pragma unroll
        for (int u = 0; u < 8; u++) s += p[u*2304];
        kv[idx] = s;
    } else if (idx < 256*2304 + 256*48){
        int k2 = idx - 256*2304;
        int bch = k2 / 48, r = k2 - bch*48;
        const float* p = ksp + (size_t)bch*8*48 + r;
        float s = 0.f;
        #pragma unroll
        for (int u = 0; u < 8; u++) s += p[u*48];
        ksum[k2] = s;
    }
}

// attention apply: blockIdx = bch*4 + rs; 256 rows each; kv in LDS.
__global__ __launch_bounds__(256) void attn_apply(const bf16* qkv, const float* kv,
                                                  const float* ksum, bf16* out){
    __shared__ float kvs[HDIM*HDIM];
    __shared__ float kss[HDIM];
    __shared__ float qrow[16][HDIM+2];
    __shared__ float dens[16];
    int bch = blockIdx.x >> 2, rs = blockIdx.x & 3;
    int bc = bch >> 3, h = bch & 7;
    const float* kvh = kv + (size_t)bch*HDIM*HDIM;
    for (int i = threadIdx.x; i < HDIM*HDIM; i += 256) kvs[i] = kvh[i];
    if (threadIdx.x < HDIM) kss[threadIdx.x] = ksum[(size_t)bch*HDIM + threadIdx.x];
    __syncthreads();
    int rr = threadIdx.x >> 4;
    int ff = threadIdx.x & 15;
    for (int r0 = rs*256; r0 < rs*256 + 256; r0 += 16){
        for (int i = threadIdx.x; i < 16*HDIM; i += 256){
            int r = i/HDIM, e = i%HDIM;
            qrow[r][e] = b2f(qkv[(size_t)(bc*GSZ + r0 + r)*TD + h*HDIM + e]);
        }
        __syncthreads();
        if (ff == 0){
            float s = 0.f;
            #pragma unroll
            for (int e = 0; e < HDIM; e++) s += qrow[rr][e]*kss[e];
            dens[rr] = s + 1e-8f;
        }
        __syncthreads();
        float inv = 1.f / dens[rr];
        float o0 = 0.f, o1 = 0.f, o2 = 0.f;
        #pragma unroll 8
        for (int e = 0; e < HDIM; e++){
            float qe = qrow[rr][e];
            o0 += qe*kvs[e*HDIM + ff];
            o1 += qe*kvs[e*HDIM + ff + 16];
            o2 += qe*kvs[e*HDIM + ff + 32];
        }
        bf16* orow = out + (size_t)(bc*GSZ + r0 + rr)*DD + h*HDIM;
        orow[ff]      = f2b(o0*inv);
        orow[ff + 16] = f2b(o1*inv);
        orow[ff + 32] = f2b(o2*inv);
        __syncthreads();
    }
}

// wi[tok,d] = img^T + aot*cs  (aot already in natural order)
__global__ void build_wi(const float* img, const bf16* aot,
                         const float* cs, float* wi){
    __shared__ float tile[32][33];
    int b = blockIdx.z, p0 = blockIdx.x*32, d0 = blockIdx.y*32;
    int tx = threadIdx.x, ty = threadIdx.y;
    #pragma unroll
    for (int i = 0; i < 32; i += 8)
        tile[ty+i][tx] = img[((size_t)b*DD + d0+ty+i)*NPIX + p0+tx];
    __syncthreads();
    #pragma unroll
    for (int i = 0; i < 32; i += 8){
        int p = p0 + ty + i;
        size_t t = (size_t)(b<<12) + p;
        float a = b2f(aot[t*DD + d0+tx]);
        wi[t*DD + d0+tx] = tile[tx][ty+i] + a*cs[d0+tx];
    }
}

__global__ void colsq_partial(const float* x, float* partial){
    int b = blockIdx.x / 32, chunk = blockIdx.x % 32;
    float acc0 = 0.f, acc1 = 0.f;
    for (int r = 0; r < 128; r++){
        const float* row = x + ((size_t)((b<<12) + chunk*128 + r))*DD;
        float v = row[threadIdx.x]; acc0 += v*v;
        if (threadIdx.x < 128){ float w = row[threadIdx.x + 256]; acc1 += w*w; }
    }
    partial[(size_t)blockIdx.x*DD + threadIdx.x] = acc0;
    if (threadIdx.x < 128) partial[(size_t)blockIdx.x*DD + threadIdx.x + 256] = acc1;
}

__global__ void gx_from_partial(const float* partial, float* gx, int nd){
    int i = blockIdx.x * blockDim.x + threadIdx.x;
    if (i >= nd) return;
    int b = i / DD, d = i % DD;
    float s = 0.f;
    for (int c = 0; c < 32; c++) s += partial[((size_t)(b*32 + c))*DD + d];
    gx[i] = sqrtf(s);
}

__global__ void final_out(const float* img, const float* wi, const bf16* fot,
                          const float* ffs, const float* fins, float* out){
    __shared__ float tile[32][33];
    int b = blockIdx.z, p0 = blockIdx.x*32, d0 = blockIdx.y*32;
    int tx = threadIdx.x, ty = threadIdx.y;
    #pragma unroll
    for (int i = 0; i < 32; i += 8){
        size_t t = (size_t)(b<<12) + p0+ty+i;
        tile[ty+i][tx] = wi[t*DD + d0+tx] + b2f(fot[t*DD + d0+tx])*ffs[d0+tx];
    }
    __syncthreads();
    #pragma unroll
    for (int i = 0; i < 32; i += 8){
        int d = d0 + ty + i;
        size_t o = ((size_t)b*DD + d)*NPIX + p0+tx;
        out[o] = img[o] + tile[tx][ty+i]*fins[d];
    }
}

// ---------------- launch ----------------
extern "C" void kernel_launch(void* const* d_in, const int* in_sizes, int n_in,
                              void* d_out, int out_size, void* d_ws, size_t ws_size,
                              hipStream_t stream){
    const float* image   = (const float*)d_in[0];
    const float* film    = (const float*)d_in[1];
    const int*   perm    = (const int*)  d_in[2];
    const float* Wq      = (const float*)d_in[3];
    const float* bq      = (const float*)d_in[4];
    const float* Wk      = (const float*)d_in[5];
    const float* bk      = (const float*)d_in[6];
    const float* Wv      = (const float*)d_in[7];
    const float* bv      = (const float*)d_in[8];
    const float* Wo      = (const float*)d_in[9];
    const float* bo      = (const float*)d_in[10];
    const float* lnq_g   = (const float*)d_in[11];
    const float* lnq_b   = (const float*)d_in[12];
    const float* lnk_g   = (const float*)d_in[13];
    const float* lnk_b   = (const float*)d_in[14];
    const float* ada1_W  = (const float*)d_in[15];
    const float* ada1_b  = (const float*)d_in[16];
    const float* grn1_g  = (const float*)d_in[17];
    const float* grn1_b  = (const float*)d_in[18];
    const float* ada2_W  = (const float*)d_in[19];
    const float* ada2_b  = (const float*)d_in[20];
    const float* grn2_g  = (const float*)d_in[21];
    const float* grn2_b  = (const float*)d_in[22];
    const float* conv1_W = (const float*)d_in[23];
    const float* conv1_b = (const float*)d_in[24];
    const float* conv2_W = (const float*)d_in[25];
    const float* conv2_b = (const float*)d_in[26];
    const float* cs      = (const float*)d_in[27];
    const float* ffs     = (const float*)d_in[28];
    const float* fins    = (const float*)d_in[29];
    float* out = (float*)d_out;

    // ---- workspace (~202 MB; round-4 evidence ws >= 305 MB) ----
    char* m = (char*)d_ws;
    float* gb1     = (float*)m;  m += (size_t)BB*768*4;
    float* gb2     = (float*)m;  m += (size_t)BB*768*4;
    int*   invp    = (int*)m;    m += (size_t)NPIX*4;
    float* gx      = (float*)m;  m += (size_t)BB*DD*4;
    float* nx      = (float*)m;  m += (size_t)BB*DD*4;
    float* kvbuf   = (float*)m;  m += (size_t)256*HDIM*HDIM*4;
    float* ksumbuf = (float*)m;  m += (size_t)256*HDIM*4;
    float* partial = (float*)m;  m += (size_t)BB*32*DD*4;
    float* kvp     = (float*)m;  m += (size_t)2048*2304*4;        // 18.9 MB
    float* ksp     = (float*)m;  m += (size_t)2048*48*4;
    float* bqkv    = (float*)m;  m += (size_t)TD*4;
    bf16*  wb      = (bf16*)m;   m += (size_t)(4*WSEG + 2*WBIG)*2;
    bf16*  wqkv = wb;                       // q,k,v rows = first 3 segments
    bf16*  wbo  = wb + 3*WSEG;
    bf16*  wb1  = wb + 4*WSEG, *wb2 = wb + 4*WSEG + WBIG;
    bf16* qkv = (bf16*)m;        m += (size_t)TT*TD*2;            // 75.5 MB
    bf16* obf = (bf16*)m;        m += (size_t)TT*DD*2;            // 25.2 MB
    bf16* abf = (bf16*)m;        m += (size_t)TT*DD*2;            // 25.2 MB
    float* wi = (float*)m;       m += (size_t)TT*DD*4;            // 50.3 MB
    bf16* H1  = qkv;             // 32768 x 1536 bf16 = qkv+obf exactly

    // ---- prologue ----
    conv_w<<<6912, 256, 0, stream>>>(Wq, Wk, Wv, Wo, conv1_W, conv2_W, wb);
    make_bias<<<5, 256, 0, stream>>>(bq, bk, bv, bqkv);
    film_gemm<<<48, 256, 0, stream>>>(film, ada1_W, ada1_b, ada2_W, ada2_b, gb1, gb2);
    make_invp<<<16, 256, 0, stream>>>(perm, invp);

    // ---- branch 1: cloud attention ----
    rownorm<<<BB*DD, 256, 0, stream>>>(image, gx);
    grn_nx<<<BB, DD, 0, stream>>>(gx, nx);
    adaln1_transpose<<<dim3(128,12,BB), dim3(32,8), 0, stream>>>(image, nx, grn1_g, grn1_b, gb1, invp, abf);
    gemm_mfma<0><<<dim3(9,256), 256, 0, stream>>>(abf, wqkv, bqkv, qkv, TT, TD, DD, nullptr);
    ln_elu_qk<<<2*TT/4, 256, 0, stream>>>(qkv, lnq_g, lnq_b, lnk_g, lnk_b);
    kv_ksum_part<<<2048, 256, 0, stream>>>(qkv, kvp, ksp);
    kv_reduce<<<2352, 256, 0, stream>>>(kvp, ksp, kvbuf, ksumbuf);
    attn_apply<<<1024, 256, 0, stream>>>(qkv, kvbuf, ksumbuf, abf);          // attn-out -> abf
    gemm_mfma<0><<<dim3(3,256), 256, 0, stream>>>(abf, wbo, bo, obf, TT, DD, DD, perm); // scatter rows -> natural order
    build_wi<<<dim3(128,12,BB), dim3(32,8), 0, stream>>>(image, obf, cs, wi);

    // ---- branch 2: FFN ----
    colsq_partial<<<BB*32, 256, 0, stream>>>(wi, partial);
    gx_from_partial<<<12, 256, 0, stream>>>(partial, gx, BB*DD);
    grn_nx<<<BB, DD, 0, stream>>>(gx, nx);
    adaln_tok<<<(TT*DD)/256, 256, 0, stream>>>(wi, nx, grn2_g, grn2_b, gb2, abf);  // x2 -> abf
    gemm_mfma<1><<<dim3(12,256), 256, 0, stream>>>(abf, wb1, conv1_b, H1, TT, DHID, DD, nullptr);
    gemm_mfma<0><<<dim3(3,256), 256, 0, stream>>>(H1, wb2, conv2_b, abf, TT, DD, DHID, nullptr); // fo -> abf
    final_out<<<dim3(128,12,BB), dim3(32,8), 0, stream>>>(image, wi, abf, ffs, fins, out);
}

// Round 7
// 662.208 us; speedup vs baseline: 5.3720x; 1.0368x over previous
//
#include <hip/hip_runtime.h>
#include <hip/hip_bf16.h>
#include <math.h>

#define BB      8
#define DD      384
#define FDIM    256
#define NPIX    4096
#define NHEAD   8
#define NCLOUD  4
#define HDIM    48
#define GSZ     1024
#define TT      (BB*NPIX)     // 32768 tokens
#define DHID    (4*DD)        // 1536
#define TD      1152          // qkv fused row stride

typedef __hip_bfloat16 bf16;
typedef __attribute__((ext_vector_type(8))) short bf16x8;
typedef __attribute__((ext_vector_type(4))) float f32x4;

__device__ __forceinline__ float b2f(bf16 x){ return __bfloat162float(x); }
__device__ __forceinline__ bf16  f2b(float x){ return __float2bfloat16(x); }
__device__ __forceinline__ float lo2f(unsigned u){ union{unsigned i; float f;} c; c.i = u << 16; return c.f; }
__device__ __forceinline__ float hi2f(unsigned u){ union{unsigned i; float f;} c; c.i = u & 0xffff0000u; return c.f; }
__device__ __forceinline__ unsigned short f2bs(float x){ bf16 b = f2b(x); return *(unsigned short*)&b; }

#if defined(__has_builtin)
#if __has_builtin(__builtin_amdgcn_global_load_lds)
#define USE_GLL 1
#endif
#endif
#ifndef USE_GLL
#define USE_GLL 0
#endif

typedef __attribute__((address_space(1))) void gas_t;
typedef __attribute__((address_space(3))) void las_t;
__device__ __forceinline__ void gload16(const void* g, void* l){
#if USE_GLL
    __builtin_amdgcn_global_load_lds((gas_t*)(void*)g, (las_t*)l, 16, 0, 0);
#else
    *(bf16x8*)l = *(const bf16x8*)g;
#endif
}

// ---------------- block reduction helper ----------------
__device__ __forceinline__ float block_sum(float v, float* sm, int nthreads){
    #pragma unroll
    for (int o = 32; o > 0; o >>= 1) v += __shfl_down(v, o, 64);
    int nw = nthreads >> 6;
    __syncthreads();
    if ((threadIdx.x & 63) == 0) sm[threadIdx.x >> 6] = v;
    __syncthreads();
    float s = sm[0];
    for (int i = 1; i < nw; i++) s += sm[i];
    return s;
}

// ---------------- weight fp32 -> bf16 (once per launch) ----------------
#define WSEG 147456            // 384*384
#define WBIG 589824            // 1536*384
__global__ void conv_w(const float* Wq, const float* Wk, const float* Wv, const float* Wo,
                       const float* W1, const float* W2, bf16* dst){
    int i = blockIdx.x*256 + threadIdx.x;          // < 1769472 exact
    float v;
    if      (i <   WSEG) v = Wq[i];
    else if (i < 2*WSEG) v = Wk[i -   WSEG];
    else if (i < 3*WSEG) v = Wv[i - 2*WSEG];
    else if (i < 4*WSEG) v = Wo[i - 3*WSEG];
    else if (i < 4*WSEG + WBIG) v = W1[i - 4*WSEG];
    else v = W2[i - 4*WSEG - WBIG];
    dst[i] = f2b(v);
}

__global__ void make_bias(const float* bq, const float* bk, const float* bv, float* bqkv){
    int i = blockIdx.x*256 + threadIdx.x;
    if (i < 384) bqkv[i] = bq[i];
    else if (i < 768) bqkv[i] = bk[i-384];
    else if (i < 1152) bqkv[i] = bv[i-768];
}

// ---------------- tiny kernels ----------------
__global__ void film_gemm(const float* film, const float* W1, const float* b1,
                          const float* W2, const float* b2, float* gb1, float* gb2){
    int idx = blockIdx.x * blockDim.x + threadIdx.x;
    if (idx >= 2*BB*768) return;
    int which = idx / (BB*768);
    int r = idx % (BB*768);
    int bb = r / 768, j = r % 768;
    const float* W = which ? W2 : W1;
    const float* bi = which ? b2 : b1;
    const float* f = film + bb*FDIM;
    const float* w = W + (size_t)j*FDIM;
    float s = 0.f;
    for (int i = 0; i < FDIM; i++) s += f[i]*w[i];
    (which ? gb2 : gb1)[bb*768 + j] = s + bi[j];
}

__global__ void make_invp(const int* perm, int* invp){
    int i = blockIdx.x * blockDim.x + threadIdx.x;
    if (i < NPIX) invp[perm[i]] = i;
}

// gx[b*D+d] = sqrt(sum_pix x^2), float4 loads
__global__ void rownorm(const float* x, float* gx){
    __shared__ float sm[4];
    int row = blockIdx.x;
    const float4* p = (const float4*)(x + (size_t)row*NPIX);
    float s = 0.f;
    for (int i = threadIdx.x; i < NPIX/4; i += 256){
        float4 v = p[i];
        s += v.x*v.x + v.y*v.y + v.z*v.z + v.w*v.w;
    }
    float tot = block_sum(s, sm, 256);
    if (threadIdx.x == 0) gx[row] = sqrtf(tot);
}

__global__ void grn_nx(const float* gx, float* nx){
    __shared__ float sm[6];
    int b = blockIdx.x; int d = threadIdx.x;
    float g = gx[b*DD + d];
    float tot = block_sum(g, sm, 384);
    nx[b*DD + d] = g / (tot/(float)DD + 1e-6f);
}

// transpose + GRN1 + adaLN1 + pixel shuffle -> bf16 rows in SHUFFLED order
__global__ void adaln1_transpose(const float* img, const float* nx,
                                 const float* gg, const float* gbv,
                                 const float* gb, const int* invp, bf16* xt){
    __shared__ float tile[32][33];
    int b = blockIdx.z, p0 = blockIdx.x*32, d0 = blockIdx.y*32;
    int tx = threadIdx.x, ty = threadIdx.y;
    #pragma unroll
    for (int i = 0; i < 32; i += 8)
        tile[ty+i][tx] = img[((size_t)b*DD + d0+ty+i)*NPIX + p0+tx];
    __syncthreads();
    #pragma unroll
    for (int i = 0; i < 32; i += 8){
        int p = p0 + ty + i;
        int j = invp[p];
        int d = d0 + tx;
        float v = tile[tx][ty+i];
        float g = v * nx[b*DD + d];
        float grn = (1.f + gg[d])*g + gbv[d] + v;
        xt[((size_t)(b<<12) + j)*DD + d] = f2b(grn*(1.f + gb[b*768 + d]) + gb[b*768 + 384 + d]);
    }
}

// GRN2 + adaLN2: bf16 in -> bf16 out
__global__ void adaln_tok(const bf16* xin, const float* nx,
                          const float* gg, const float* gbv,
                          const float* gb, bf16* xout){
    size_t i = (size_t)blockIdx.x * blockDim.x + threadIdx.x;
    int d = (int)(i % DD); size_t t = i / DD; int b = (int)(t >> 12);
    float v = b2f(xin[i]);
    float g = v * nx[b*DD + d];
    float grn = (1.f + gg[d])*g + gbv[d] + v;
    xout[i] = f2b(grn*(1.f + gb[b*768 + d]) + gb[b*768 + 384 + d]);
}

// ---------------- MFMA bf16 GEMM:  C = A[M,K] @ W[N,K]^T + bias ----------------
// 128x128 tile, BK=32, 4 waves 2x2, global_load_lds staging with
// bank-deconflict seg-rotation swizzle: chunk(r,k4) at index 4r + ((k4 + (r>>2))&3).
// XCD-aware block remap: each XCD owns a contiguous 32-band y-range.
template<int EPI>   // 0 none, 1 silu
__global__ __launch_bounds__(256) void gemm_mfma(const bf16* __restrict__ A,
                          const bf16* __restrict__ W,
                          const float* __restrict__ bias,
                          bf16* __restrict__ C,
                          int M, int N, int K, const int* __restrict__ rowmap){
    __shared__ short lds_[8192];
    int tid  = threadIdx.x;
    int lane = tid & 63, wid = tid >> 6;
    int quad = lane >> 4, l16 = lane & 15;
    int wm = (wid >> 1) * 64, wn = (wid & 1) * 64;

    // XCD remap (gridDim.y == 256): v%8 ~ XCD; give each XCD y in [k*32,(k+1)*32)
    int v = blockIdx.y * gridDim.x + blockIdx.x;
    int xcd = v & 7, ii = v >> 3;
    int by = xcd * 32 + ii / gridDim.x;
    int bx = ii % gridDim.x;
    int m0 = by * 128, n0 = bx * 128;

    // swizzled read offsets (loop-invariant): jj = (quad + (l16>>2)) & 3
    int jj = (quad + (l16 >> 2)) & 3;

    f32x4 acc[4][4] = {};
    for (int k0 = 0; k0 < K; k0 += 32){
        #pragma unroll
        for (int it = 0; it < 4; it++){
            int s = tid + it*256;
            int half = s >> 9;
            int sl = s & 511;
            int r = sl >> 2;
            int j = sl & 3;
            int k4 = (j - ((r >> 2) & 3)) & 3;
            const bf16* src = half ? (W + (size_t)(n0 + r)*K + k0 + k4*8)
                                   : (A + (size_t)(m0 + r)*K + k0 + k4*8);
            gload16(src, lds_ + (size_t)s*8);
        }
        __syncthreads();
        bf16x8 af[4], wf[4];
        #pragma unroll
        for (int t = 0; t < 4; t++){
            int ra = wm + t*16 + l16;
            int rw = wn + t*16 + l16;
            af[t] = *(const bf16x8*)(void*)(lds_ + (ra*4 + jj)*8);
            wf[t] = *(const bf16x8*)(void*)(lds_ + 4096 + (rw*4 + jj)*8);
        }
        #pragma unroll
        for (int i = 0; i < 4; i++)
            #pragma unroll
            for (int j2 = 0; j2 < 4; j2++)
                acc[i][j2] = __builtin_amdgcn_mfma_f32_16x16x32_bf16(af[i], wf[j2], acc[i][j2], 0, 0, 0);
        __syncthreads();
    }
    #pragma unroll
    for (int j2 = 0; j2 < 4; j2++){
        int col = n0 + wn + j2*16 + l16;
        float bs = bias[col];
        #pragma unroll
        for (int i = 0; i < 4; i++){
            int rowb = m0 + wm + i*16 + quad*4;
            #pragma unroll
            for (int r = 0; r < 4; r++){
                int row = rowb + r;
                int grow = rowmap ? ((row & ~4095) | rowmap[row & 4095]) : row;
                float vv = acc[i][j2][r] + bs;
                if (EPI == 1) vv = vv / (1.f + __expf(-vv));
                C[(size_t)grow*N + col] = f2b(vv);
            }
        }
    }
}

// LN over D=384 + elu + 1 for q and k inside fused qkv buffer. One wave per row.
// Vectorized: each lane handles 3 uints (6 bf16), d = lane*6 .. lane*6+5.
__global__ __launch_bounds__(256) void ln_elu_qk(bf16* qkv,
                        const float* gq, const float* bq2,
                        const float* gk, const float* bk2){
    int r = blockIdx.x*4 + (threadIdx.x >> 6);     // 0 .. 2*TT
    int lane = threadIdx.x & 63;
    int t = r >> 1, which = r & 1;
    unsigned* row32 = (unsigned*)(qkv + (size_t)t*TD + which*384);
    const float* g = which ? gk : gq;
    const float* b = which ? bk2 : bq2;
    unsigned u[3];
    #pragma unroll
    for (int i = 0; i < 3; i++) u[i] = row32[lane*3 + i];
    float vv[6];
    #pragma unroll
    for (int i = 0; i < 3; i++){ vv[2*i] = lo2f(u[i]); vv[2*i+1] = hi2f(u[i]); }
    float s = 0.f;
    #pragma unroll
    for (int i = 0; i < 6; i++) s += vv[i];
    #pragma unroll
    for (int o = 32; o > 0; o >>= 1) s += __shfl_xor(s, o, 64);
    float mean = s / (float)DD;
    float s2 = 0.f;
    #pragma unroll
    for (int i = 0; i < 6; i++){ float d = vv[i]-mean; s2 += d*d; }
    #pragma unroll
    for (int o = 32; o > 0; o >>= 1) s2 += __shfl_xor(s2, o, 64);
    float rstd = rsqrtf(s2/(float)DD + 1e-5f);
    int d0 = lane*6;
    unsigned short us[6];
    #pragma unroll
    for (int i = 0; i < 6; i++){
        float y = (vv[i]-mean)*rstd*g[d0+i] + b[d0+i];
        y = (y > 0.f) ? y : expm1f(y);
        us[i] = f2bs(y + 1.f);
    }
    #pragma unroll
    for (int i = 0; i < 3; i++) row32[lane*3 + i] = (unsigned)us[2*i] | ((unsigned)us[2*i+1] << 16);
}

// kv partial: blockIdx = bch*8 + sub; each handles 128 n-rows; 3x3 register tile.
__global__ __launch_bounds__(256) void kv_ksum_part(const bf16* qkv, float* kvp, float* ksp){
    int bch = blockIdx.x >> 3, sub = blockIdx.x & 7;
    int bc = bch >> 3, h = bch & 7;
    __shared__ float ks[16][49];
    __shared__ float vs[16][49];
    int eg = (threadIdx.x >> 4) * 3;
    int fg = (threadIdx.x & 15) * 3;
    float acc[3][3] = {};
    float ksacc[3] = {};
    int nbase = bc*GSZ + sub*128;
    for (int n0 = 0; n0 < 128; n0 += 16){
        for (int i = threadIdx.x; i < 16*48; i += 256){
            int n = i/48, e = i%48;
            size_t base = (size_t)(nbase + n0 + n)*TD + h*HDIM;
            ks[n][e] = b2f(qkv[base + 384 + e]);
            vs[n][e] = b2f(qkv[base + 768 + e]);
        }
        __syncthreads();
        #pragma unroll 4
        for (int n = 0; n < 16; n++){
            float ka[3], vb[3];
            #pragma unroll
            for (int i = 0; i < 3; i++){ ka[i] = ks[n][eg+i]; vb[i] = vs[n][fg+i]; }
            #pragma unroll
            for (int i = 0; i < 3; i++)
                #pragma unroll
                for (int j = 0; j < 3; j++)
                    acc[i][j] += ka[i]*vb[j];
            if ((threadIdx.x & 15) == 0){
                #pragma unroll
                for (int i = 0; i < 3; i++) ksacc[i] += ka[i];
            }
        }
        __syncthreads();
    }
    float* kvo = kvp + (size_t)blockIdx.x*2304;
    #pragma unroll
    for (int i = 0; i < 3; i++)
        #pragma unroll
        for (int j = 0; j < 3; j++)
            kvo[(eg+i)*48 + fg+j] = acc[i][j];
    if ((threadIdx.x & 15) == 0){
        #pragma unroll
        for (int i = 0; i < 3; i++) ksp[(size_t)blockIdx.x*48 + eg+i] = ksacc[i];
    }
}

__global__ void kv_reduce(const float* kvp, const float* ksp, float* kv, float* ksum){
    int idx = blockIdx.x*256 + threadIdx.x;
    if (idx < 256*2304){
        int bch = idx / 2304, r = idx - bch*2304;
        const float* p = kvp + (size_t)bch*8*2304 + r;
        float s = 0.f;
        #pragma unroll
        for (int u = 0; u < 8; u++) s += p[u*2304];
        kv[idx] = s;
    } else if (idx < 256*2304 + 256*48){
        int k2 = idx - 256*2304;
        int bch = k2 / 48, r = k2 - bch*48;
        const float* p = ksp + (size_t)bch*8*48 + r;
        float s = 0.f;
        #pragma unroll
        for (int u = 0; u < 8; u++) s += p[u*48];
        ksum[k2] = s;
    }
}

// attention apply: blockIdx = bch*4 + rs; 256 rows each; kv in LDS.
__global__ __launch_bounds__(256) void attn_apply(const bf16* qkv, const float* kv,
                                                  const float* ksum, bf16* out){
    __shared__ float kvs[HDIM*HDIM];
    __shared__ float kss[HDIM];
    __shared__ float qrow[16][HDIM+2];
    __shared__ float dens[16];
    int bch = blockIdx.x >> 2, rs = blockIdx.x & 3;
    int bc = bch >> 3, h = bch & 7;
    const float* kvh = kv + (size_t)bch*HDIM*HDIM;
    for (int i = threadIdx.x; i < HDIM*HDIM; i += 256) kvs[i] = kvh[i];
    if (threadIdx.x < HDIM) kss[threadIdx.x] = ksum[(size_t)bch*HDIM + threadIdx.x];
    __syncthreads();
    int rr = threadIdx.x >> 4;
    int ff = threadIdx.x & 15;
    for (int r0 = rs*256; r0 < rs*256 + 256; r0 += 16){
        for (int i = threadIdx.x; i < 16*HDIM; i += 256){
            int r = i/HDIM, e = i%HDIM;
            qrow[r][e] = b2f(qkv[(size_t)(bc*GSZ + r0 + r)*TD + h*HDIM + e]);
        }
        __syncthreads();
        if (ff == 0){
            float s = 0.f;
            #pragma unroll
            for (int e = 0; e < HDIM; e++) s += qrow[rr][e]*kss[e];
            dens[rr] = s + 1e-8f;
        }
        __syncthreads();
        float inv = 1.f / dens[rr];
        float o0 = 0.f, o1 = 0.f, o2 = 0.f;
        #pragma unroll 8
        for (int e = 0; e < HDIM; e++){
            float qe = qrow[rr][e];
            o0 += qe*kvs[e*HDIM + ff];
            o1 += qe*kvs[e*HDIM + ff + 16];
            o2 += qe*kvs[e*HDIM + ff + 32];
        }
        bf16* orow = out + (size_t)(bc*GSZ + r0 + rr)*DD + h*HDIM;
        orow[ff]      = f2b(o0*inv);
        orow[ff + 16] = f2b(o1*inv);
        orow[ff + 32] = f2b(o2*inv);
        __syncthreads();
    }
}

// wi[tok,d] = img^T + aot*cs  (bf16 out)
__global__ void build_wi(const float* img, const bf16* aot,
                         const float* cs, bf16* wi){
    __shared__ float tile[32][33];
    int b = blockIdx.z, p0 = blockIdx.x*32, d0 = blockIdx.y*32;
    int tx = threadIdx.x, ty = threadIdx.y;
    #pragma unroll
    for (int i = 0; i < 32; i += 8)
        tile[ty+i][tx] = img[((size_t)b*DD + d0+ty+i)*NPIX + p0+tx];
    __syncthreads();
    #pragma unroll
    for (int i = 0; i < 32; i += 8){
        int p = p0 + ty + i;
        size_t t = (size_t)(b<<12) + p;
        float a = b2f(aot[t*DD + d0+tx]);
        wi[t*DD + d0+tx] = f2b(tile[tx][ty+i] + a*cs[d0+tx]);
    }
}

__global__ void colsq_partial(const bf16* x, float* partial){
    int b = blockIdx.x / 32, chunk = blockIdx.x % 32;
    float acc0 = 0.f, acc1 = 0.f;
    for (int r = 0; r < 128; r++){
        const bf16* row = x + ((size_t)((b<<12) + chunk*128 + r))*DD;
        float v = b2f(row[threadIdx.x]); acc0 += v*v;
        if (threadIdx.x < 128){ float w = b2f(row[threadIdx.x + 256]); acc1 += w*w; }
    }
    partial[(size_t)blockIdx.x*DD + threadIdx.x] = acc0;
    if (threadIdx.x < 128) partial[(size_t)blockIdx.x*DD + threadIdx.x + 256] = acc1;
}

__global__ void gx_from_partial(const float* partial, float* gx, int nd){
    int i = blockIdx.x * blockDim.x + threadIdx.x;
    if (i >= nd) return;
    int b = i / DD, d = i % DD;
    float s = 0.f;
    for (int c = 0; c < 32; c++) s += partial[((size_t)(b*32 + c))*DD + d];
    gx[i] = sqrtf(s);
}

__global__ void final_out(const float* img, const bf16* wi, const bf16* fot,
                          const float* ffs, const float* fins, float* out){
    __shared__ float tile[32][33];
    int b = blockIdx.z, p0 = blockIdx.x*32, d0 = blockIdx.y*32;
    int tx = threadIdx.x, ty = threadIdx.y;
    #pragma unroll
    for (int i = 0; i < 32; i += 8){
        size_t t = (size_t)(b<<12) + p0+ty+i;
        tile[ty+i][tx] = b2f(wi[t*DD + d0+tx]) + b2f(fot[t*DD + d0+tx])*ffs[d0+tx];
    }
    __syncthreads();
    #pragma unroll
    for (int i = 0; i < 32; i += 8){
        int d = d0 + ty + i;
        size_t o = ((size_t)b*DD + d)*NPIX + p0+tx;
        out[o] = img[o] + tile[tx][ty+i]*fins[d];
    }
}

// ---------------- launch ----------------
extern "C" void kernel_launch(void* const* d_in, const int* in_sizes, int n_in,
                              void* d_out, int out_size, void* d_ws, size_t ws_size,
                              hipStream_t stream){
    const float* image   = (const float*)d_in[0];
    const float* film    = (const float*)d_in[1];
    const int*   perm    = (const int*)  d_in[2];
    const float* Wq      = (const float*)d_in[3];
    const float* bq      = (const float*)d_in[4];
    const float* Wk      = (const float*)d_in[5];
    const float* bk      = (const float*)d_in[6];
    const float* Wv      = (const float*)d_in[7];
    const float* bv      = (const float*)d_in[8];
    const float* Wo      = (const float*)d_in[9];
    const float* bo      = (const float*)d_in[10];
    const float* lnq_g   = (const float*)d_in[11];
    const float* lnq_b   = (const float*)d_in[12];
    const float* lnk_g   = (const float*)d_in[13];
    const float* lnk_b   = (const float*)d_in[14];
    const float* ada1_W  = (const float*)d_in[15];
    const float* ada1_b  = (const float*)d_in[16];
    const float* grn1_g  = (const float*)d_in[17];
    const float* grn1_b  = (const float*)d_in[18];
    const float* ada2_W  = (const float*)d_in[19];
    const float* ada2_b  = (const float*)d_in[20];
    const float* grn2_g  = (const float*)d_in[21];
    const float* grn2_b  = (const float*)d_in[22];
    const float* conv1_W = (const float*)d_in[23];
    const float* conv1_b = (const float*)d_in[24];
    const float* conv2_W = (const float*)d_in[25];
    const float* conv2_b = (const float*)d_in[26];
    const float* cs      = (const float*)d_in[27];
    const float* ffs     = (const float*)d_in[28];
    const float* fins    = (const float*)d_in[29];
    float* out = (float*)d_out;

    // ---- workspace (~180 MB; round-4 evidence ws >= 305 MB) ----
    char* m = (char*)d_ws;
    float* gb1     = (float*)m;  m += (size_t)BB*768*4;
    float* gb2     = (float*)m;  m += (size_t)BB*768*4;
    int*   invp    = (int*)m;    m += (size_t)NPIX*4;
    float* gx      = (float*)m;  m += (size_t)BB*DD*4;
    float* nx      = (float*)m;  m += (size_t)BB*DD*4;
    float* kvbuf   = (float*)m;  m += (size_t)256*HDIM*HDIM*4;
    float* ksumbuf = (float*)m;  m += (size_t)256*HDIM*4;
    float* partial = (float*)m;  m += (size_t)BB*32*DD*4;
    float* kvp     = (float*)m;  m += (size_t)2048*2304*4;        // 18.9 MB
    float* ksp     = (float*)m;  m += (size_t)2048*48*4;
    float* bqkv    = (float*)m;  m += (size_t)TD*4;
    bf16*  wb      = (bf16*)m;   m += (size_t)(4*WSEG + 2*WBIG)*2;
    bf16*  wqkv = wb;
    bf16*  wbo  = wb + 3*WSEG;
    bf16*  wb1  = wb + 4*WSEG, *wb2 = wb + 4*WSEG + WBIG;
    bf16* qkv = (bf16*)m;        m += (size_t)TT*TD*2;            // 75.5 MB
    bf16* obf = (bf16*)m;        m += (size_t)TT*DD*2;            // 25.2 MB
    bf16* abf = (bf16*)m;        m += (size_t)TT*DD*2;            // 25.2 MB
    bf16* wi  = (bf16*)m;        m += (size_t)TT*DD*2;            // 25.2 MB
    bf16* H1  = qkv;             // 32768 x 1536 bf16 = qkv+obf exactly

    // ---- prologue ----
    conv_w<<<6912, 256, 0, stream>>>(Wq, Wk, Wv, Wo, conv1_W, conv2_W, wb);
    make_bias<<<5, 256, 0, stream>>>(bq, bk, bv, bqkv);
    film_gemm<<<48, 256, 0, stream>>>(film, ada1_W, ada1_b, ada2_W, ada2_b, gb1, gb2);
    make_invp<<<16, 256, 0, stream>>>(perm, invp);

    // ---- branch 1: cloud attention ----
    rownorm<<<BB*DD, 256, 0, stream>>>(image, gx);
    grn_nx<<<BB, DD, 0, stream>>>(gx, nx);
    adaln1_transpose<<<dim3(128,12,BB), dim3(32,8), 0, stream>>>(image, nx, grn1_g, grn1_b, gb1, invp, abf);
    gemm_mfma<0><<<dim3(9,256), 256, 0, stream>>>(abf, wqkv, bqkv, qkv, TT, TD, DD, nullptr);
    ln_elu_qk<<<2*TT/4, 256, 0, stream>>>(qkv, lnq_g, lnq_b, lnk_g, lnk_b);
    kv_ksum_part<<<2048, 256, 0, stream>>>(qkv, kvp, ksp);
    kv_reduce<<<2352, 256, 0, stream>>>(kvp, ksp, kvbuf, ksumbuf);
    attn_apply<<<1024, 256, 0, stream>>>(qkv, kvbuf, ksumbuf, abf);          // attn-out -> abf
    gemm_mfma<0><<<dim3(3,256), 256, 0, stream>>>(abf, wbo, bo, obf, TT, DD, DD, perm); // scatter rows -> natural order
    build_wi<<<dim3(128,12,BB), dim3(32,8), 0, stream>>>(image, obf, cs, wi);

    // ---- branch 2: FFN ----
    colsq_partial<<<BB*32, 256, 0, stream>>>(wi, partial);
    gx_from_partial<<<12, 256, 0, stream>>>(partial, gx, BB*DD);
    grn_nx<<<BB, DD, 0, stream>>>(gx, nx);
    adaln_tok<<<(TT*DD)/256, 256, 0, stream>>>(wi, nx, grn2_g, grn2_b, gb2, abf);  // x2 -> abf
    gemm_mfma<1><<<dim3(12,256), 256, 0, stream>>>(abf, wb1, conv1_b, H1, TT, DHID, DD, nullptr);
    gemm_mfma<0><<<dim3(3,256), 256, 0, stream>>>(H1, wb2, conv2_b, abf, TT, DD, DHID, nullptr); // fo -> abf
    final_out<<<dim3(128,12,BB), dim3(32,8), 0, stream>>>(image, wi, abf, ffs, fins, out);
}

// Round 8
// 607.273 us; speedup vs baseline: 5.8579x; 1.0905x over previous
//
#include <hip/hip_runtime.h>
#include <hip/hip_bf16.h>
#include <math.h>

#define BB      8
#define DD      384
#define FDIM    256
#define NPIX    4096
#define NHEAD   8
#define NCLOUD  4
#define HDIM    48
#define GSZ     1024
#define TT      (BB*NPIX)     // 32768 tokens
#define DHID    (4*DD)        // 1536
#define TD      1152          // qkv fused row stride

typedef __hip_bfloat16 bf16;
typedef __attribute__((ext_vector_type(8))) short bf16x8;
typedef __attribute__((ext_vector_type(4))) float f32x4;

__device__ __forceinline__ float b2f(bf16 x){ return __bfloat162float(x); }
__device__ __forceinline__ bf16  f2b(float x){ return __float2bfloat16(x); }
__device__ __forceinline__ float lo2f(unsigned u){ union{unsigned i; float f;} c; c.i = u << 16; return c.f; }
__device__ __forceinline__ float hi2f(unsigned u){ union{unsigned i; float f;} c; c.i = u & 0xffff0000u; return c.f; }
__device__ __forceinline__ unsigned short f2bs(float x){ bf16 b = f2b(x); return *(unsigned short*)&b; }
__device__ __forceinline__ unsigned pack2(float a, float b){
    return (unsigned)f2bs(a) | ((unsigned)f2bs(b) << 16);
}

#if defined(__has_builtin)
#if __has_builtin(__builtin_amdgcn_global_load_lds)
#define USE_GLL 1
#endif
#endif
#ifndef USE_GLL
#define USE_GLL 0
#endif

typedef __attribute__((address_space(1))) void gas_t;
typedef __attribute__((address_space(3))) void las_t;
__device__ __forceinline__ void gload16(const void* g, void* l){
#if USE_GLL
    __builtin_amdgcn_global_load_lds((gas_t*)(void*)g, (las_t*)l, 16, 0, 0);
#else
    *(bf16x8*)l = *(const bf16x8*)g;
#endif
}

// ---------------- block reduction helper ----------------
__device__ __forceinline__ float block_sum(float v, float* sm, int nthreads){
    #pragma unroll
    for (int o = 32; o > 0; o >>= 1) v += __shfl_down(v, o, 64);
    int nw = nthreads >> 6;
    __syncthreads();
    if ((threadIdx.x & 63) == 0) sm[threadIdx.x >> 6] = v;
    __syncthreads();
    float s = sm[0];
    for (int i = 1; i < nw; i++) s += sm[i];
    return s;
}

// ---------------- fused prologue: weights->bf16, film GEMM, invp, bias, zero stats ----------------
#define WSEG 147456            // 384*384
#define WBIG 589824            // 1536*384
__global__ void prologue(const float* Wq, const float* Wk, const float* Wv, const float* Wo,
                         const float* W1, const float* W2, bf16* wb,
                         const float* film, const float* ada1_W, const float* ada1_b,
                         const float* ada2_W, const float* ada2_b, float* gb1, float* gb2,
                         const int* perm, int* invp,
                         const float* bq, const float* bk, const float* bv, float* bqkv,
                         float* gxsq, float* gxsq2){
    int blk = blockIdx.x, tid = threadIdx.x;
    if (blk < 6912){
        int i = blk*256 + tid;
        float v;
        if      (i <   WSEG) v = Wq[i];
        else if (i < 2*WSEG) v = Wk[i -   WSEG];
        else if (i < 3*WSEG) v = Wv[i - 2*WSEG];
        else if (i < 4*WSEG) v = Wo[i - 3*WSEG];
        else if (i < 4*WSEG + WBIG) v = W1[i - 4*WSEG];
        else v = W2[i - 4*WSEG - WBIG];
        wb[i] = f2b(v);
    } else if (blk < 6960){
        int idx = (blk-6912)*256 + tid;           // < 12288
        int which = idx / (BB*768);
        int r = idx % (BB*768);
        int bb = r / 768, j = r % 768;
        const float* W = which ? ada2_W : ada1_W;
        const float* bi = which ? ada2_b : ada1_b;
        const float* f = film + bb*FDIM;
        const float* w = W + (size_t)j*FDIM;
        float s = 0.f;
        for (int i = 0; i < FDIM; i++) s += f[i]*w[i];
        (which ? gb2 : gb1)[bb*768 + j] = s + bi[j];
    } else if (blk < 6976){
        int i = (blk-6960)*256 + tid;
        if (i < NPIX) invp[perm[i]] = i;
    } else if (blk < 6981){
        int i = (blk-6976)*256 + tid;
        if (i < 384) bqkv[i] = bq[i];
        else if (i < 768) bqkv[i] = bk[i-384];
        else if (i < 1152) bqkv[i] = bv[i-768];
    } else {
        int i = (blk-6981)*256 + tid;             // 12 blocks -> 3072
        if (i < BB*DD){ gxsq[i] = 0.f; gxsq2[i] = 0.f; }
    }
}

// ---------------- prep1: img fp32 -> imgT bf16 (token-major) + per-(b,d) sumsq ----------------
__global__ void prep1(const float* img, bf16* imgT, float* gxsq){
    __shared__ float tile[32][33];
    __shared__ float red[32][8];
    int b = blockIdx.z, p0 = blockIdx.x*32, d0 = blockIdx.y*32;
    int tx = threadIdx.x, ty = threadIdx.y;     // 32 x 8
    #pragma unroll
    for (int i = 0; i < 32; i += 8)
        tile[ty+i][tx] = img[((size_t)b*DD + d0+ty+i)*NPIX + p0+tx];   // tile[d_local][pix_local]
    __syncthreads();
    #pragma unroll
    for (int i = 0; i < 32; i += 8){
        int p = p0 + ty + i;
        imgT[((size_t)(b<<12) + p)*DD + d0+tx] = f2b(tile[tx][ty+i]);
    }
    float s = 0.f;
    #pragma unroll
    for (int k = 0; k < 4; k++){ float v = tile[tx][ty*4 + k]; s += v*v; }
    red[tx][ty] = s;
    __syncthreads();
    if (ty == 0){
        float t2 = 0.f;
        #pragma unroll
        for (int k = 0; k < 8; k++) t2 += red[tx][k];
        atomicAdd(&gxsq[b*DD + d0+tx], t2);
    }
}

// nx[b,d] = gx / (mean_d gx + 1e-6); optionally sqrt input first
template<bool SQ>
__global__ void grn_nx(const float* gin, float* nx){
    __shared__ float sm[6];
    int b = blockIdx.x; int d = threadIdx.x;
    float g = gin[b*DD + d];
    if (SQ) g = sqrtf(g);
    float tot = block_sum(g, sm, 384);
    nx[b*DD + d] = g / (tot/(float)DD + 1e-6f);
}

// adaLN1: wave per token; read imgT row, GRN1+film, write to SHUFFLED slot
__global__ __launch_bounds__(256) void adaln1_tok(const bf16* imgT, const float* nx,
                        const float* gg, const float* gbv, const float* gb,
                        const int* invp, bf16* xt){
    int t = blockIdx.x*4 + (threadIdx.x >> 6);
    int lane = threadIdx.x & 63;
    int b = t >> 12, p = t & 4095;
    int j = invp[p];
    const unsigned* src = (const unsigned*)(imgT + (size_t)t*DD);
    unsigned* dst = (unsigned*)(xt + ((size_t)(b<<12) + j)*DD);
    int d0 = lane*6;
    const float* nxp = nx + b*DD + d0;
    const float* g1 = gb + b*768 + d0;
    const float* g2 = gb + b*768 + 384 + d0;
    #pragma unroll
    for (int i = 0; i < 3; i++){
        unsigned u = src[lane*3 + i];
        float v0 = lo2f(u), v1 = hi2f(u);
        int dd0 = 2*i, dd1 = 2*i+1;
        float r0 = ((1.f + gg[d0+dd0])*(v0*nxp[dd0]) + gbv[d0+dd0] + v0)*(1.f + g1[dd0]) + g2[dd0];
        float r1 = ((1.f + gg[d0+dd1])*(v1*nxp[dd1]) + gbv[d0+dd1] + v1)*(1.f + g1[dd1]) + g2[dd1];
        dst[lane*3 + i] = pack2(r0, r1);
    }
}

// adaLN2: wave per token, no shuffle
__global__ __launch_bounds__(256) void adaln2_tok(const bf16* wi, const float* nx,
                        const float* gg, const float* gbv, const float* gb, bf16* xout){
    int t = blockIdx.x*4 + (threadIdx.x >> 6);
    int lane = threadIdx.x & 63;
    int b = t >> 12;
    const unsigned* src = (const unsigned*)(wi + (size_t)t*DD);
    unsigned* dst = (unsigned*)(xout + (size_t)t*DD);
    int d0 = lane*6;
    const float* nxp = nx + b*DD + d0;
    const float* g1 = gb + b*768 + d0;
    const float* g2 = gb + b*768 + 384 + d0;
    #pragma unroll
    for (int i = 0; i < 3; i++){
        unsigned u = src[lane*3 + i];
        float v0 = lo2f(u), v1 = hi2f(u);
        int dd0 = 2*i, dd1 = 2*i+1;
        float r0 = ((1.f + gg[d0+dd0])*(v0*nxp[dd0]) + gbv[d0+dd0] + v0)*(1.f + g1[dd0]) + g2[dd0];
        float r1 = ((1.f + gg[d0+dd1])*(v1*nxp[dd1]) + gbv[d0+dd1] + v1)*(1.f + g1[dd1]) + g2[dd1];
        dst[lane*3 + i] = pack2(r0, r1);
    }
}

// ---------------- MFMA bf16 GEMM:  C = A[M,K] @ W[N,K]^T + bias ----------------
// 128x128 tile, BK=32, 4 waves 2x2, GLL staging, XCD y-band remap,
// hoisted staging pointers + per-row epilogue bases.
template<int EPI>   // 0 none, 1 silu
__global__ __launch_bounds__(256) void gemm_mfma(const bf16* __restrict__ A,
                          const bf16* __restrict__ W,
                          const float* __restrict__ bias,
                          bf16* __restrict__ C,
                          int M, int N, int K, const int* __restrict__ rowmap){
    __shared__ short lds_[8192];
    int tid  = threadIdx.x;
    int lane = tid & 63, wid = tid >> 6;
    int quad = lane >> 4, l16 = lane & 15;
    int wm = (wid >> 1) * 64, wn = (wid & 1) * 64;

    int v = blockIdx.y * gridDim.x + blockIdx.x;
    int xcd = v & 7, ii = v >> 3;
    int by = xcd * 32 + ii / gridDim.x;
    int bx = ii % gridDim.x;
    int m0 = by * 128, n0 = bx * 128;

    // hoisted staging source/dest
    const bf16* sp[4]; short* lp[4];
    #pragma unroll
    for (int it = 0; it < 4; it++){
        int s = tid + it*256;
        int half = s >> 9;
        int r = (s >> 2) & 127;
        int seg = s & 3;
        sp[it] = (half ? W + (size_t)(n0 + r)*K : A + (size_t)(m0 + r)*K) + seg*8;
        lp[it] = lds_ + (size_t)s*8;
    }

    f32x4 acc[4][4] = {};
    for (int k0 = 0; k0 < K; k0 += 32){
        #pragma unroll
        for (int it = 0; it < 4; it++) gload16(sp[it] + k0, lp[it]);
        __syncthreads();
        bf16x8 af[4], wf[4];
        #pragma unroll
        for (int t = 0; t < 4; t++){
            af[t] = *(const bf16x8*)(void*)(lds_ + (wm + t*16 + l16)*32 + quad*8);
            wf[t] = *(const bf16x8*)(void*)(lds_ + 4096 + (wn + t*16 + l16)*32 + quad*8);
        }
        #pragma unroll
        for (int i = 0; i < 4; i++)
            #pragma unroll
            for (int j2 = 0; j2 < 4; j2++)
                acc[i][j2] = __builtin_amdgcn_mfma_f32_16x16x32_bf16(af[i], wf[j2], acc[i][j2], 0, 0, 0);
        __syncthreads();
    }
    int colbase = n0 + wn + l16;
    float bs[4];
    #pragma unroll
    for (int j2 = 0; j2 < 4; j2++) bs[j2] = bias[colbase + j2*16];
    #pragma unroll
    for (int i = 0; i < 4; i++){
        #pragma unroll
        for (int r = 0; r < 4; r++){
            int row = m0 + wm + i*16 + quad*4 + r;
            int grow = rowmap ? ((row & ~4095) | rowmap[row & 4095]) : row;
            bf16* cp = C + (size_t)grow*N + colbase;
            #pragma unroll
            for (int j2 = 0; j2 < 4; j2++){
                float vv = acc[i][j2][r] + bs[j2];
                if (EPI == 1) vv = vv / (1.f + __expf(-vv));
                cp[j2*16] = f2b(vv);
            }
        }
    }
}

// LN over D=384 + elu + 1 for q and k inside fused qkv buffer. One wave per row.
__global__ __launch_bounds__(256) void ln_elu_qk(bf16* qkv,
                        const float* gq, const float* bq2,
                        const float* gk, const float* bk2){
    int r = blockIdx.x*4 + (threadIdx.x >> 6);
    int lane = threadIdx.x & 63;
    int t = r >> 1, which = r & 1;
    unsigned* row32 = (unsigned*)(qkv + (size_t)t*TD + which*384);
    const float* g = which ? gk : gq;
    const float* b = which ? bk2 : bq2;
    unsigned u[3];
    #pragma unroll
    for (int i = 0; i < 3; i++) u[i] = row32[lane*3 + i];
    float vv[6];
    #pragma unroll
    for (int i = 0; i < 3; i++){ vv[2*i] = lo2f(u[i]); vv[2*i+1] = hi2f(u[i]); }
    float s = 0.f;
    #pragma unroll
    for (int i = 0; i < 6; i++) s += vv[i];
    #pragma unroll
    for (int o = 32; o > 0; o >>= 1) s += __shfl_xor(s, o, 64);
    float mean = s / (float)DD;
    float s2 = 0.f;
    #pragma unroll
    for (int i = 0; i < 6; i++){ float d = vv[i]-mean; s2 += d*d; }
    #pragma unroll
    for (int o = 32; o > 0; o >>= 1) s2 += __shfl_xor(s2, o, 64);
    float rstd = rsqrtf(s2/(float)DD + 1e-5f);
    int d0 = lane*6;
    #pragma unroll
    for (int i = 0; i < 3; i++){
        float y0 = (vv[2*i]-mean)*rstd*g[d0+2*i] + b[d0+2*i];
        float y1 = (vv[2*i+1]-mean)*rstd*g[d0+2*i+1] + b[d0+2*i+1];
        y0 = (y0 > 0.f) ? y0 : expm1f(y0);
        y1 = (y1 > 0.f) ? y1 : expm1f(y1);
        row32[lane*3 + i] = pack2(y0 + 1.f, y1 + 1.f);
    }
}

// kv partial: blockIdx = bch*8 + sub; each handles 128 n-rows; 3x3 register tile.
__global__ __launch_bounds__(256) void kv_ksum_part(const bf16* qkv, float* kvp, float* ksp){
    int bch = blockIdx.x >> 3, sub = blockIdx.x & 7;
    int bc = bch >> 3, h = bch & 7;
    __shared__ float ks[16][49];
    __shared__ float vs[16][49];
    int eg = (threadIdx.x >> 4) * 3;
    int fg = (threadIdx.x & 15) * 3;
    float acc[3][3] = {};
    float ksacc[3] = {};
    int nbase = bc*GSZ + sub*128;
    for (int n0 = 0; n0 < 128; n0 += 16){
        for (int i = threadIdx.x; i < 16*48; i += 256){
            int n = i/48, e = i%48;
            size_t base = (size_t)(nbase + n0 + n)*TD + h*HDIM;
            ks[n][e] = b2f(qkv[base + 384 + e]);
            vs[n][e] = b2f(qkv[base + 768 + e]);
        }
        __syncthreads();
        #pragma unroll 4
        for (int n = 0; n < 16; n++){
            float ka[3], vb[3];
            #pragma unroll
            for (int i = 0; i < 3; i++){ ka[i] = ks[n][eg+i]; vb[i] = vs[n][fg+i]; }
            #pragma unroll
            for (int i = 0; i < 3; i++)
                #pragma unroll
                for (int j = 0; j < 3; j++)
                    acc[i][j] += ka[i]*vb[j];
            if ((threadIdx.x & 15) == 0){
                #pragma unroll
                for (int i = 0; i < 3; i++) ksacc[i] += ka[i];
            }
        }
        __syncthreads();
    }
    float* kvo = kvp + (size_t)blockIdx.x*2304;
    #pragma unroll
    for (int i = 0; i < 3; i++)
        #pragma unroll
        for (int j = 0; j < 3; j++)
            kvo[(eg+i)*48 + fg+j] = acc[i][j];
    if ((threadIdx.x & 15) == 0){
        #pragma unroll
        for (int i = 0; i < 3; i++) ksp[(size_t)blockIdx.x*48 + eg+i] = ksacc[i];
    }
}

__global__ void kv_reduce(const float* kvp, const float* ksp, float* kv, float* ksum){
    int idx = blockIdx.x*256 + threadIdx.x;
    if (idx < 256*2304){
        int bch = idx / 2304, r = idx - bch*2304;
        const float* p = kvp + (size_t)bch*8*2304 + r;
        float s = 0.f;
        #pragma unroll
        for (int u = 0; u < 8; u++) s += p[u*2304];
        kv[idx] = s;
    } else if (idx < 256*2304 + 256*48){
        int k2 = idx - 256*2304;
        int bch = k2 / 48, r = k2 - bch*48;
        const float* p = ksp + (size_t)bch*8*48 + r;
        float s = 0.f;
        #pragma unroll
        for (int u = 0; u < 8; u++) s += p[u*48];
        ksum[k2] = s;
    }
}

// attention apply: blockIdx = bch*4 + rs; 256 rows each; kv in LDS.
__global__ __launch_bounds__(256) void attn_apply(const bf16* qkv, const float* kv,
                                                  const float* ksum, bf16* out){
    __shared__ float kvs[HDIM*HDIM];
    __shared__ float kss[HDIM];
    __shared__ float qrow[16][HDIM+2];
    __shared__ float dens[16];
    int bch = blockIdx.x >> 2, rs = blockIdx.x & 3;
    int bc = bch >> 3, h = bch & 7;
    const float* kvh = kv + (size_t)bch*HDIM*HDIM;
    for (int i = threadIdx.x; i < HDIM*HDIM; i += 256) kvs[i] = kvh[i];
    if (threadIdx.x < HDIM) kss[threadIdx.x] = ksum[(size_t)bch*HDIM + threadIdx.x];
    __syncthreads();
    int rr = threadIdx.x >> 4;
    int ff = threadIdx.x & 15;
    for (int r0 = rs*256; r0 < rs*256 + 256; r0 += 16){
        for (int i = threadIdx.x; i < 16*HDIM; i += 256){
            int r = i/HDIM, e = i%HDIM;
            qrow[r][e] = b2f(qkv[(size_t)(bc*GSZ + r0 + r)*TD + h*HDIM + e]);
        }
        __syncthreads();
        if (ff == 0){
            float s = 0.f;
            #pragma unroll
            for (int e = 0; e < HDIM; e++) s += qrow[rr][e]*kss[e];
            dens[rr] = s + 1e-8f;
        }
        __syncthreads();
        float inv = 1.f / dens[rr];
        float o0 = 0.f, o1 = 0.f, o2 = 0.f;
        #pragma unroll 8
        for (int e = 0; e < HDIM; e++){
            float qe = qrow[rr][e];
            o0 += qe*kvs[e*HDIM + ff];
            o1 += qe*kvs[e*HDIM + ff + 16];
            o2 += qe*kvs[e*HDIM + ff + 32];
        }
        bf16* orow = out + (size_t)(bc*GSZ + r0 + rr)*DD + h*HDIM;
        orow[ff]      = f2b(o0*inv);
        orow[ff + 16] = f2b(o1*inv);
        orow[ff + 32] = f2b(o2*inv);
        __syncthreads();
    }
}

// build wi (bf16, token-major) + accumulate GRN2 sumsq; wave per token-batch.
__global__ __launch_bounds__(256) void build_wi_colsq(const bf16* imgT, const bf16* aot,
                        const float* cs, bf16* wi, float* gxsq2){
    __shared__ float red[4][DD];
    int wave = threadIdx.x >> 6, lane = threadIdx.x & 63;
    int t0 = blockIdx.x*128 + wave*32;
    int b = (blockIdx.x*128) >> 12;
    int d0 = lane*6;
    float c[6];
    #pragma unroll
    for (int i = 0; i < 6; i++) c[i] = cs[d0+i];
    float acc[6] = {};
    for (int it = 0; it < 32; it++){
        size_t t = (size_t)(t0 + it);
        const unsigned* pi = (const unsigned*)(imgT + t*DD);
        const unsigned* pa = (const unsigned*)(aot + t*DD);
        unsigned* pw = (unsigned*)(wi + t*DD);
        #pragma unroll
        for (int i = 0; i < 3; i++){
            unsigned ui = pi[lane*3 + i];
            unsigned ua = pa[lane*3 + i];
            float v0 = lo2f(ui) + lo2f(ua)*c[2*i];
            float v1 = hi2f(ui) + hi2f(ua)*c[2*i+1];
            acc[2*i]   += v0*v0;
            acc[2*i+1] += v1*v1;
            pw[lane*3 + i] = pack2(v0, v1);
        }
    }
    #pragma unroll
    for (int i = 0; i < 6; i++) red[wave][d0+i] = acc[i];
    __syncthreads();
    for (int d = threadIdx.x; d < DD; d += 256){
        float s = red[0][d] + red[1][d] + red[2][d] + red[3][d];
        atomicAdd(&gxsq2[b*DD + d], s);
    }
}

__global__ void final_out(const float* img, const bf16* wi, const bf16* fot,
                          const float* ffs, const float* fins, float* out){
    __shared__ float tile[32][33];
    int b = blockIdx.z, p0 = blockIdx.x*32, d0 = blockIdx.y*32;
    int tx = threadIdx.x, ty = threadIdx.y;
    #pragma unroll
    for (int i = 0; i < 32; i += 8){
        size_t t = (size_t)(b<<12) + p0+ty+i;
        tile[ty+i][tx] = b2f(wi[t*DD + d0+tx]) + b2f(fot[t*DD + d0+tx])*ffs[d0+tx];
    }
    __syncthreads();
    #pragma unroll
    for (int i = 0; i < 32; i += 8){
        int d = d0 + ty + i;
        size_t o = ((size_t)b*DD + d)*NPIX + p0+tx;
        out[o] = img[o] + tile[tx][ty+i]*fins[d];
    }
}

// ---------------- launch ----------------
extern "C" void kernel_launch(void* const* d_in, const int* in_sizes, int n_in,
                              void* d_out, int out_size, void* d_ws, size_t ws_size,
                              hipStream_t stream){
    const float* image   = (const float*)d_in[0];
    const float* film    = (const float*)d_in[1];
    const int*   perm    = (const int*)  d_in[2];
    const float* Wq      = (const float*)d_in[3];
    const float* bq      = (const float*)d_in[4];
    const float* Wk      = (const float*)d_in[5];
    const float* bk      = (const float*)d_in[6];
    const float* Wv      = (const float*)d_in[7];
    const float* bv      = (const float*)d_in[8];
    const float* Wo      = (const float*)d_in[9];
    const float* bo      = (const float*)d_in[10];
    const float* lnq_g   = (const float*)d_in[11];
    const float* lnq_b   = (const float*)d_in[12];
    const float* lnk_g   = (const float*)d_in[13];
    const float* lnk_b   = (const float*)d_in[14];
    const float* ada1_W  = (const float*)d_in[15];
    const float* ada1_b  = (const float*)d_in[16];
    const float* grn1_g  = (const float*)d_in[17];
    const float* grn1_b  = (const float*)d_in[18];
    const float* ada2_W  = (const float*)d_in[19];
    const float* ada2_b  = (const float*)d_in[20];
    const float* grn2_g  = (const float*)d_in[21];
    const float* grn2_b  = (const float*)d_in[22];
    const float* conv1_W = (const float*)d_in[23];
    const float* conv1_b = (const float*)d_in[24];
    const float* conv2_W = (const float*)d_in[25];
    const float* conv2_b = (const float*)d_in[26];
    const float* cs      = (const float*)d_in[27];
    const float* ffs     = (const float*)d_in[28];
    const float* fins    = (const float*)d_in[29];
    float* out = (float*)d_out;

    // ---- workspace (~205 MB; ws >= 305 MB per round-4 evidence) ----
    char* m = (char*)d_ws;
    float* gb1     = (float*)m;  m += (size_t)BB*768*4;
    float* gb2     = (float*)m;  m += (size_t)BB*768*4;
    int*   invp    = (int*)m;    m += (size_t)NPIX*4;
    float* gxsq    = (float*)m;  m += (size_t)BB*DD*4;
    float* gxsq2   = (float*)m;  m += (size_t)BB*DD*4;
    float* nx      = (float*)m;  m += (size_t)BB*DD*4;
    float* kvbuf   = (float*)m;  m += (size_t)256*HDIM*HDIM*4;
    float* ksumbuf = (float*)m;  m += (size_t)256*HDIM*4;
    float* kvp     = (float*)m;  m += (size_t)2048*2304*4;        // 18.9 MB
    float* ksp     = (float*)m;  m += (size_t)2048*48*4;
    float* bqkv    = (float*)m;  m += (size_t)TD*4;
    bf16*  wb      = (bf16*)m;   m += (size_t)(4*WSEG + 2*WBIG)*2;
    bf16*  wqkv = wb;
    bf16*  wbo  = wb + 3*WSEG;
    bf16*  wb1  = wb + 4*WSEG, *wb2 = wb + 4*WSEG + WBIG;
    bf16* imgT = (bf16*)m;       m += (size_t)TT*DD*2;            // 25.2 MB
    bf16* qkv = (bf16*)m;        m += (size_t)TT*TD*2;            // 75.5 MB
    bf16* obf = (bf16*)m;        m += (size_t)TT*DD*2;            // 25.2 MB
    bf16* abf = (bf16*)m;        m += (size_t)TT*DD*2;            // 25.2 MB
    bf16* wi  = (bf16*)m;        m += (size_t)TT*DD*2;            // 25.2 MB
    bf16* H1  = qkv;             // 32768 x 1536 bf16 = qkv+obf exactly

    // ---- prologue (fused) ----
    prologue<<<6993, 256, 0, stream>>>(Wq, Wk, Wv, Wo, conv1_W, conv2_W, wb,
                                       film, ada1_W, ada1_b, ada2_W, ada2_b, gb1, gb2,
                                       perm, invp, bq, bk, bv, bqkv, gxsq, gxsq2);

    // ---- branch 1: cloud attention ----
    prep1<<<dim3(128,12,BB), dim3(32,8), 0, stream>>>(image, imgT, gxsq);
    grn_nx<true><<<BB, DD, 0, stream>>>(gxsq, nx);
    adaln1_tok<<<TT/4, 256, 0, stream>>>(imgT, nx, grn1_g, grn1_b, gb1, invp, abf);
    gemm_mfma<0><<<dim3(9,256), 256, 0, stream>>>(abf, wqkv, bqkv, qkv, TT, TD, DD, nullptr);
    ln_elu_qk<<<2*TT/4, 256, 0, stream>>>(qkv, lnq_g, lnq_b, lnk_g, lnk_b);
    kv_ksum_part<<<2048, 256, 0, stream>>>(qkv, kvp, ksp);
    kv_reduce<<<2352, 256, 0, stream>>>(kvp, ksp, kvbuf, ksumbuf);
    attn_apply<<<1024, 256, 0, stream>>>(qkv, kvbuf, ksumbuf, abf);          // attn-out -> abf
    gemm_mfma<0><<<dim3(3,256), 256, 0, stream>>>(abf, wbo, bo, obf, TT, DD, DD, perm); // scatter -> natural order
    build_wi_colsq<<<BB*32, 256, 0, stream>>>(imgT, obf, cs, wi, gxsq2);

    // ---- branch 2: FFN ----
    grn_nx<true><<<BB, DD, 0, stream>>>(gxsq2, nx);
    adaln2_tok<<<TT/4, 256, 0, stream>>>(wi, nx, grn2_g, grn2_b, gb2, abf);  // x2 -> abf
    gemm_mfma<1><<<dim3(12,256), 256, 0, stream>>>(abf, wb1, conv1_b, H1, TT, DHID, DD, nullptr);
    gemm_mfma<0><<<dim3(3,256), 256, 0, stream>>>(H1, wb2, conv2_b, abf, TT, DD, DHID, nullptr); // fo -> abf
    final_out<<<dim3(128,12,BB), dim3(32,8), 0, stream>>>(image, wi, abf, ffs, fins, out);
}